// Round 1
// baseline (1077.516 us; speedup 1.0000x reference)
//
#include <hip/hip_runtime.h>
#include <hip/hip_bf16.h>
#include <stdint.h>

typedef unsigned short u16;
typedef unsigned int   u32;
typedef unsigned long long u64;
typedef __attribute__((ext_vector_type(4))) float f32x4;
typedef __attribute__((ext_vector_type(8))) short s16x8;

#define NEG_INF (-1e9f)

__device__ __forceinline__ u16 f2bf(float f) {
  __hip_bfloat16 h = __float2bfloat16(f);
  return __builtin_bit_cast(u16, h);
}

__device__ __forceinline__ f32x4 mfma16(s16x8 a, s16x8 b, f32x4 c) {
  return __builtin_amdgcn_mfma_f32_16x16x32_bf16(a, b, c, 0, 0, 0);
}

// ---------------------------------------------------------------- mask prep
// Detect whether mask elements are 1 byte (np.bool_) or 4 bytes (int32).
__global__ void detect_mask_kernel(const u32* __restrict__ mraw, u32* __restrict__ flag) {
  __shared__ int any;
  if (threadIdx.x == 0) any = 0;
  __syncthreads();
  int loc = 0;
  for (int i = threadIdx.x; i < 16384; i += 256) {
    u32 v = mraw[i];
    if (v & 0xFFFFFF00u) loc = 1;  // int32 0/1 values never set high bytes
  }
  if (loc) atomicOr(&any, 1);
  __syncthreads();
  if (threadIdx.x == 0) *flag = any ? 1u : 4u;
}

// Pack mask into bitmask bytes: maskb[(b*T+t)*64 + ch] bit i <-> n = ch*8+i, 1 = masked
__global__ __launch_bounds__(256) void maskprep_kernel(const void* __restrict__ mraw,
                                                       const u32* __restrict__ flag,
                                                       unsigned char* __restrict__ mb) {
  long long idx = (long long)blockIdx.x * 256 + threadIdx.x;  // B*T*64 = 2097152
  long long bt = idx >> 6;
  int ch = (int)(idx & 63);
  unsigned char byte = 0;
  if (*flag == 1) {
    u64 v = *(const u64*)((const unsigned char*)mraw + bt * 512 + ch * 8);
#pragma unroll
    for (int i = 0; i < 8; i++)
      if ((v >> (8 * i)) & 0xFFull) byte |= (unsigned char)(1 << i);
  } else {
    const int* p = (const int*)mraw + bt * 512 + ch * 8;
#pragma unroll
    for (int i = 0; i < 8; i++)
      if (p[i]) byte |= (unsigned char)(1 << i);
  }
  mb[idx] = byte;
}

// ---------------------------------------------------------------- weight prep
// out[i][j] = (j < kreal ? in[j*ld_in + off + i] : 0), out row-major [RO][CO]
__global__ void transpose_cvt_kernel(const float* __restrict__ in, int ld_in, int off,
                                     int kreal, int CO, u16* __restrict__ outp) {
  int i = blockIdx.x;
  for (int j = threadIdx.x; j < CO; j += 256) {
    float v = (j < kreal) ? in[(long long)j * ld_in + off + i] : 0.0f;
    outp[(long long)i * CO + j] = f2bf(v);
  }
}

// W2bf[d][h] = W_kvlogit[d][1024+h]  (no transpose)
__global__ void slice_cvt_kernel(const float* __restrict__ in, u16* __restrict__ outp) {
  long long idx = (long long)blockIdx.x * 256 + threadIdx.x;  // 262144
  long long dd = idx >> 9;
  int hh = (int)(idx & 511);
  outp[idx] = f2bf(in[dd * 1536 + 1024 + hh]);
}

// ---------------------------------------------------------------- mean / fixed ctx
__global__ __launch_bounds__(256) void pmean_kernel(const float* __restrict__ emb,
                                                    float* __restrict__ pmean) {
  int bq = blockIdx.x >> 2, nq = blockIdx.x & 3;
  const float* src = emb + ((long long)bq * 512 + nq * 128) * 512;
  float s0 = 0.f, s1 = 0.f;
  for (int n = 0; n < 128; ++n) {
    s0 += src[(long long)n * 512 + threadIdx.x];
    s1 += src[(long long)n * 512 + threadIdx.x + 256];
  }
  float* dst = pmean + (long long)blockIdx.x * 512;
  dst[threadIdx.x] = s0;
  dst[threadIdx.x + 256] = s1;
}

__global__ __launch_bounds__(256) void fixedctx_kernel(const float* __restrict__ pmean,
                                                       const float* __restrict__ Wc,
                                                       float* __restrict__ fixedc) {
  __shared__ float mf[512];
  int b = blockIdx.x;
  const float* p = pmean + (long long)b * 4 * 512;
  for (int d = threadIdx.x; d < 512; d += 256)
    mf[d] = (p[d] + p[512 + d] + p[1024 + d] + p[1536 + d]) * (1.0f / 512.0f);
  __syncthreads();
  for (int h = threadIdx.x; h < 512; h += 256) {
    float s = 0.f;
    for (int d = 0; d < 512; ++d) s += mf[d] * Wc[(long long)d * 512 + h];
    fixedc[(long long)b * 512 + h] = s;
  }
}

// ---------------------------------------------------------------- next-node features
// nextn[b*128+t][0..511] = emb[b, cur[b,t], :]; [512..514] = scalars; [515..543] = 0
__global__ __launch_bounds__(256) void build_nextn_kernel(
    const float* __restrict__ emb, const int* __restrict__ cur,
    const float* __restrict__ ucap, const float* __restrict__ ubat,
    const float* __restrict__ ctim, u16* __restrict__ outp) {
  long long rowm = blockIdx.x;  // 0..32767
  int b = (int)(rowm >> 7);
  int node = cur[rowm];
  const float* src = emb + ((long long)b * 512 + node) * 512;
  u16* dst = outp + rowm * 544;
  for (int c = threadIdx.x; c < 544; c += 256) {
    float v;
    if (c < 512)       v = src[c];
    else if (c == 512) v = 1.0f - ucap[rowm];
    else if (c == 513) v = 1.0f - ubat[rowm];
    else if (c == 514) v = ctim[rowm];
    else               v = 0.0f;
    dst[c] = f2bf(v);
  }
}

// ---------------------------------------------------------------- generic 128^2 MFMA GEMM
// C[m][n] = sum_k A[m][k] * B[n][k]   (both operands row-major with K contiguous)
// EPI: 0 = scatter to Kbuf/Vtbuf, 1 = +fixed_context -> query bf16,
//      2 = plain bf16 [m][512],  3 = logits: scale/tanh/mask -> f32 d_out
template <int AF32, int BF32, int EPI, int BATCHB>
__global__ __launch_bounds__(256) void gemm128_kernel(
    const void* __restrict__ Av, const void* __restrict__ Bv,
    int ldA, int ldB, int K, long long strideBbytes,
    void* __restrict__ out0, void* __restrict__ out1, const void* __restrict__ aux) {
  __shared__ u16 lA[128 * 32];
  __shared__ u16 lB[128 * 32];
  const int tid = threadIdx.x;
  const int lane = tid & 63;
  const int wave = tid >> 6;
  const int wr = wave >> 1, wc = wave & 1;
  const int mtile = blockIdx.y, ntile = blockIdx.x;
  const long long arow0 = (long long)mtile * 128;
  const long long brow0 = (long long)ntile * 128;
  const char* Abase = (const char*)Av;
  const char* Bbase = (const char*)Bv;
  if (BATCHB) Bbase += (long long)mtile * strideBbytes;

  f32x4 acc[4][4];
#pragma unroll
  for (int i = 0; i < 4; i++)
#pragma unroll
    for (int j = 0; j < 4; j++) acc[i][j] = (f32x4){0.f, 0.f, 0.f, 0.f};

  const int r = tid >> 2;          // 0..63 staging row
  const int c8 = (tid & 3) << 3;   // k offset (elements)

  for (int k0 = 0; k0 < K; k0 += 32) {
    __syncthreads();
#pragma unroll
    for (int hh = 0; hh < 2; ++hh) {
      const int row = hh * 64 + r;
      if (AF32) {
        const float* src = (const float*)Abase + (arow0 + row) * (long long)ldA + k0 + c8;
        f32x4 v0 = *(const f32x4*)src;
        f32x4 v1 = *(const f32x4*)(src + 4);
        s16x8 pk;
        pk[0] = (short)f2bf(v0[0]); pk[1] = (short)f2bf(v0[1]);
        pk[2] = (short)f2bf(v0[2]); pk[3] = (short)f2bf(v0[3]);
        pk[4] = (short)f2bf(v1[0]); pk[5] = (short)f2bf(v1[1]);
        pk[6] = (short)f2bf(v1[2]); pk[7] = (short)f2bf(v1[3]);
        *(s16x8*)&lA[row * 32 + c8] = pk;
      } else {
        const u16* src = (const u16*)Abase + (arow0 + row) * (long long)ldA + k0 + c8;
        *(s16x8*)&lA[row * 32 + c8] = *(const s16x8*)src;
      }
      if (BF32) {
        const float* src = (const float*)Bbase + (brow0 + row) * (long long)ldB + k0 + c8;
        f32x4 v0 = *(const f32x4*)src;
        f32x4 v1 = *(const f32x4*)(src + 4);
        s16x8 pk;
        pk[0] = (short)f2bf(v0[0]); pk[1] = (short)f2bf(v0[1]);
        pk[2] = (short)f2bf(v0[2]); pk[3] = (short)f2bf(v0[3]);
        pk[4] = (short)f2bf(v1[0]); pk[5] = (short)f2bf(v1[1]);
        pk[6] = (short)f2bf(v1[2]); pk[7] = (short)f2bf(v1[3]);
        *(s16x8*)&lB[row * 32 + c8] = pk;
      } else {
        const u16* src = (const u16*)Bbase + (brow0 + row) * (long long)ldB + k0 + c8;
        *(s16x8*)&lB[row * 32 + c8] = *(const s16x8*)src;
      }
    }
    __syncthreads();
    s16x8 af[4], bfr[4];
#pragma unroll
    for (int i = 0; i < 4; i++)
      af[i] = *(const s16x8*)&lA[(wr * 64 + i * 16 + (lane & 15)) * 32 + ((lane >> 4) << 3)];
#pragma unroll
    for (int j = 0; j < 4; j++)
      bfr[j] = *(const s16x8*)&lB[(wc * 64 + j * 16 + (lane & 15)) * 32 + ((lane >> 4) << 3)];
#pragma unroll
    for (int i = 0; i < 4; i++)
#pragma unroll
      for (int j = 0; j < 4; j++) acc[i][j] = mfma16(af[i], bfr[j], acc[i][j]);
  }

  // epilogue: element (row, col) = (arow0 + wr*64+i*16+(lane>>4)*4+q, brow0 + wc*64+j*16+(lane&15))
  const float rs512 = 0.044194173824159216f;  // 1/sqrt(512)
#pragma unroll
  for (int i = 0; i < 4; i++) {
    const int rl = wr * 64 + i * 16 + ((lane >> 4) << 2);
#pragma unroll
    for (int j = 0; j < 4; j++) {
      const int cl = wc * 64 + j * 16 + (lane & 15);
      const long long col = brow0 + cl;
#pragma unroll
      for (int q = 0; q < 4; q++) {
        const long long row = arow0 + rl + q;
        float v = acc[i][j][q];
        if (EPI == 0) {
          const int bb = (int)(row >> 9);
          const int node = (int)(row & 511);
          const int part = (int)(col >> 9);
          const int hh = (int)((col >> 6) & 7);
          const int kk = (int)(col & 63);
          if (part == 0)
            ((u16*)out0)[(((long long)(bb * 8 + hh) * 512 + node) << 6) + kk] = f2bf(v);
          else
            ((u16*)out1)[(((long long)(bb * 8 + hh) * 64 + kk) << 9) + node] = f2bf(v);
        } else if (EPI == 1) {
          const float* fc = (const float*)aux;
          const int bb = (int)(row >> 7);
          ((u16*)out0)[row * 512 + col] = f2bf(v + fc[(long long)bb * 512 + col]);
        } else if (EPI == 2) {
          ((u16*)out0)[row * 512 + col] = f2bf(v);
        } else {
          const unsigned char* mb = (const unsigned char*)aux;
          const int bb = (int)(row >> 7);
          const int tt = (int)(row & 127);
          float x = v * rs512;
          float e = exp2f(x * 2.8853900817779268f);  // 2*log2(e)
          float th = 1.0f - 2.0f * __builtin_amdgcn_rcpf(e + 1.0f);
          float lg = 10.0f * th;
          u64 w = ((const u64*)mb)[((long long)(bb * 128 + tt)) * 8 + (col >> 6)];
          if ((w >> (col & 63)) & 1ull) lg = NEG_INF;
          ((float*)out0)[row * 512 + col] = lg;
        }
      }
    }
  }
}

// ---------------------------------------------------------------- fused attention
// Per block: one (b, head, t-tile of 32). Computes S^T = K*Q^T (MFMA), no-max exp softmax
// with bitmask, P staged in XOR-swizzled LDS, PV via MFMA, normalized by rowsum.
__global__ __launch_bounds__(256) void attn_kernel(
    const u16* __restrict__ query, const u16* __restrict__ Kbuf,
    const u16* __restrict__ Vtbuf, const u64* __restrict__ maskbits,
    u16* __restrict__ headsout) {
  const int fb = blockIdx.x;          // ((b*8+h)*4 + tt)
  const int tt = fb & 3;
  const int h = (fb >> 2) & 7;
  const int b = fb >> 5;
  const int tid = threadIdx.x;
  const int lane = tid & 63;
  const int wave = tid >> 6;

  __shared__ u16 P[32 * 512];     // 32 KB, swizzled: byte = t*1024 + ((n*2) ^ ((t&7)<<4))
  __shared__ u64 mrows[32 * 8];   // mask bit-words for this t-tile
  __shared__ float rsw[4][32];
  __shared__ float rst[32];

  {  // stage mask words
    int t = tid >> 3, w = tid & 7;
    mrows[tid] = maskbits[(((long long)b * 128) + tt * 32 + t) * 8 + w];
  }

  // Q fragments (B-operand; t is the output-column axis of S^T)
  const u16* Qb = query + ((long long)(b * 128 + tt * 32)) * 512 + h * 64;
  s16x8 qf[2][2];
#pragma unroll
  for (int tf = 0; tf < 2; tf++)
#pragma unroll
    for (int ks = 0; ks < 2; ks++)
      qf[tf][ks] = *(const s16x8*)(Qb + (long long)(tf * 16 + (lane & 15)) * 512 +
                                   ks * 32 + ((lane >> 4) << 3));

  // S^T = K * Q^T ; wave handles n-strip of 128
  const int ns = wave * 128;
  const u16* Kb = Kbuf + ((long long)(b * 8 + h) * 512) * 64;
  f32x4 s[8][2];
#pragma unroll
  for (int nf = 0; nf < 8; nf++)
#pragma unroll
    for (int tf = 0; tf < 2; tf++) s[nf][tf] = (f32x4){0.f, 0.f, 0.f, 0.f};
#pragma unroll
  for (int nf = 0; nf < 8; nf++) {
#pragma unroll
    for (int ks = 0; ks < 2; ks++) {
      s16x8 kf = *(const s16x8*)(Kb + (long long)(ns + nf * 16 + (lane & 15)) * 64 +
                                 ks * 32 + ((lane >> 4) << 3));
#pragma unroll
      for (int tf = 0; tf < 2; tf++) s[nf][tf] = mfma16(kf, qf[tf][ks], s[nf][tf]);
    }
  }
  __syncthreads();  // mrows visible; P free

  // exp (no max; |compat| is small by construction), mask->0, pack P, row sums
  const float CE = 0.18033688011112043f;  // (1/8) * log2(e)
  const int tcol = lane & 15;
  float psum[2] = {0.f, 0.f};
#pragma unroll
  for (int nf = 0; nf < 8; nf++) {
#pragma unroll
    for (int tf = 0; tf < 2; tf++) {
      const int trow = tf * 16 + tcol;
      const u64 w0 = mrows[trow * 8 + wave * 2];
      const u64 w1 = mrows[trow * 8 + wave * 2 + 1];
      u16 pk[4];
#pragma unroll
      for (int q = 0; q < 4; q++) {
        const int nl = nf * 16 + ((lane >> 4) << 2) + q;  // 0..127 within strip
        const u64 w = (nl & 64) ? w1 : w0;
        float p = exp2f(s[nf][tf][q] * CE);
        if ((w >> (nl & 63)) & 1ull) p = 0.0f;
        psum[tf] += p;
        pk[q] = f2bf(p);
      }
      const int nb = (ns + nf * 16 + ((lane >> 4) << 2)) * 2;  // byte col, 8B aligned
      const int off = trow * 1024 + (nb ^ ((trow & 7) << 4));
      u64 pd = (u64)pk[0] | ((u64)pk[1] << 16) | ((u64)pk[2] << 32) | ((u64)pk[3] << 48);
      *(u64*)((char*)P + off) = pd;
    }
  }
#pragma unroll
  for (int tf = 0; tf < 2; tf++) {
    float v = psum[tf];
    v += __shfl_xor(v, 16);
    v += __shfl_xor(v, 32);
    if ((lane >> 4) == 0) rsw[wave][tf * 16 + tcol] = v;
  }
  __syncthreads();
  if (tid < 32) rst[tid] = rsw[0][tid] + rsw[1][tid] + rsw[2][tid] + rsw[3][tid];
  __syncthreads();

  // O = P * V ; wave handles kk-strip of 16
  const u16* Vb = Vtbuf + ((long long)(b * 8 + h) * 64 + wave * 16) * 512;
  f32x4 o[2];
  o[0] = (f32x4){0.f, 0.f, 0.f, 0.f};
  o[1] = (f32x4){0.f, 0.f, 0.f, 0.f};
#pragma unroll
  for (int ksn = 0; ksn < 16; ksn++) {
    s16x8 vf = *(const s16x8*)(Vb + (long long)(lane & 15) * 512 + ksn * 32 + ((lane >> 4) << 3));
#pragma unroll
    for (int mf = 0; mf < 2; mf++) {
      const int trow = mf * 16 + (lane & 15);
      const int nb = (ksn * 32 + ((lane >> 4) << 3)) * 2;
      s16x8 pf = *(const s16x8*)((char*)P + trow * 1024 + (nb ^ ((trow & 7) << 4)));
      o[mf] = mfma16(pf, vf, o[mf]);
    }
  }

#pragma unroll
  for (int mf = 0; mf < 2; mf++) {
#pragma unroll
    for (int q = 0; q < 4; q++) {
      const int t = mf * 16 + ((lane >> 4) << 2) + q;
      const float ov = o[mf][q] * __builtin_amdgcn_rcpf(rst[t]);
      const long long row = (long long)b * 128 + tt * 32 + t;
      headsout[row * 512 + h * 64 + wave * 16 + (lane & 15)] = f2bf(ov);
    }
  }
}

// ---------------------------------------------------------------- log-softmax (in-place, row=512)
__global__ __launch_bounds__(256) void logsoftmax_kernel(float* __restrict__ io) {
  const long long row = (long long)blockIdx.x * 4 + (threadIdx.x >> 6);
  const int lane = threadIdx.x & 63;
  float* p = io + row * 512 + lane * 8;
  f32x4 a = *(const f32x4*)p;
  f32x4 b = *(const f32x4*)(p + 4);
  float mx = a[0];
#pragma unroll
  for (int i = 1; i < 4; i++) mx = fmaxf(mx, a[i]);
#pragma unroll
  for (int i = 0; i < 4; i++) mx = fmaxf(mx, b[i]);
#pragma unroll
  for (int d = 1; d < 64; d <<= 1) mx = fmaxf(mx, __shfl_xor(mx, d));
  const float L2E = 1.4426950408889634f;
  float s = 0.f;
#pragma unroll
  for (int i = 0; i < 4; i++) s += exp2f((a[i] - mx) * L2E);
#pragma unroll
  for (int i = 0; i < 4; i++) s += exp2f((b[i] - mx) * L2E);
#pragma unroll
  for (int d = 1; d < 64; d <<= 1) s += __shfl_xor(s, d);
  const float lse = mx + logf(s);
#pragma unroll
  for (int i = 0; i < 4; i++) a[i] -= lse;
#pragma unroll
  for (int i = 0; i < 4; i++) b[i] -= lse;
  *(f32x4*)p = a;
  *(f32x4*)(p + 4) = b;
}

// ---------------------------------------------------------------- launch
extern "C" void kernel_launch(void* const* d_in, const int* in_sizes, int n_in,
                              void* d_out, int out_size, void* d_ws, size_t ws_size,
                              hipStream_t stream) {
  (void)in_sizes; (void)n_in; (void)out_size; (void)ws_size;
  const float* emb  = (const float*)d_in[0];
  const int*   cur  = (const int*)d_in[1];
  const float* ucap = (const float*)d_in[2];
  const float* ubat = (const float*)d_in[3];
  const float* ctim = (const float*)d_in[4];
  const void*  mask = d_in[5];
  const float* Wc   = (const float*)d_in[6];
  const float* Wkvl = (const float*)d_in[7];
  const float* Wstep= (const float*)d_in[8];
  const float* Wout = (const float*)d_in[9];

  char* w = (char*)d_ws;
  size_t off = 0;
  auto take = [&](size_t nbytes) -> char* {
    char* p = w + off;
    off += (nbytes + 255) & ~(size_t)255;
    return p;
  };
  u32* flag            = (u32*)take(4);
  unsigned char* maskb = (unsigned char*)take((size_t)256 * 128 * 64);   // 2 MB
  u16* WkT             = (u16*)take((size_t)1024 * 512 * 2);
  u16* WstepT          = (u16*)take((size_t)512 * 544 * 2);
  u16* WoutT           = (u16*)take((size_t)512 * 512 * 2);
  u16* W2bf            = (u16*)take((size_t)512 * 512 * 2);
  float* pmean         = (float*)take((size_t)1024 * 512 * 4);
  float* fixedc        = (float*)take((size_t)256 * 512 * 4);
  u16* Kbuf            = (u16*)take((size_t)256 * 8 * 512 * 64 * 2);     // 134 MB
  u16* Vtbuf           = (u16*)take((size_t)256 * 8 * 64 * 512 * 2);     // 134 MB
  u16* slotA           = (u16*)take((size_t)32768 * 544 * 2);            // 35.7 MB
  u16* slotB           = (u16*)take((size_t)32768 * 512 * 2);            // 33.6 MB
  u16* nextn = slotA;      // alias chain: nextn -> headsout -> tmp
  u16* query = slotB;      // alias chain: query -> glimpse
  u16* headsout = slotA;
  u16* glimpse = slotB;
  u16* tmpb = slotA;

  detect_mask_kernel<<<1, 256, 0, stream>>>((const u32*)mask, flag);
  maskprep_kernel<<<8192, 256, 0, stream>>>(mask, flag, maskb);
  transpose_cvt_kernel<<<1024, 256, 0, stream>>>(Wkvl, 1536, 0, 512, 512, WkT);
  transpose_cvt_kernel<<<512, 256, 0, stream>>>(Wstep, 512, 0, 515, 544, WstepT);
  transpose_cvt_kernel<<<512, 256, 0, stream>>>(Wout, 512, 0, 512, 512, WoutT);
  slice_cvt_kernel<<<1024, 256, 0, stream>>>(Wkvl, W2bf);
  pmean_kernel<<<1024, 256, 0, stream>>>(emb, pmean);
  fixedctx_kernel<<<256, 256, 0, stream>>>(pmean, Wc, fixedc);
  build_nextn_kernel<<<32768, 256, 0, stream>>>(emb, cur, ucap, ubat, ctim, nextn);

  // KV projection: [131072 x 512] fp32 x WkT[1024 x 512] bf16 -> Kbuf/Vtbuf (scattered)
  gemm128_kernel<1, 0, 0, 0><<<dim3(8, 1024), 256, 0, stream>>>(
      emb, WkT, 512, 512, 512, 0, Kbuf, Vtbuf, nullptr);
  // query = fixed_context + nextn @ WstepT
  gemm128_kernel<0, 0, 1, 0><<<dim3(4, 256), 256, 0, stream>>>(
      nextn, WstepT, 544, 544, 544, 0, query, nullptr, fixedc);
  // attention
  attn_kernel<<<8192, 256, 0, stream>>>(query, Kbuf, Vtbuf, (const u64*)maskb, headsout);
  // glimpse = headsout @ WoutT
  gemm128_kernel<0, 0, 2, 0><<<dim3(4, 256), 256, 0, stream>>>(
      headsout, WoutT, 512, 512, 512, 0, glimpse, nullptr, nullptr);
  // tmp = glimpse @ W2  (factorized logit_K)
  gemm128_kernel<0, 0, 2, 0><<<dim3(4, 256), 256, 0, stream>>>(
      glimpse, W2bf, 512, 512, 512, 0, tmpb, nullptr, nullptr);
  // logits = tmp @ emb[b]^T, scaled/tanh/masked -> d_out (f32)
  gemm128_kernel<0, 1, 3, 1><<<dim3(4, 256), 256, 0, stream>>>(
      tmpb, emb, 512, 512, 512, (long long)512 * 512 * 4, d_out, nullptr, maskb);
  // in-place log-softmax
  logsoftmax_kernel<<<8192, 256, 0, stream>>>((float*)d_out);
}

// Round 2
// 880.403 us; speedup vs baseline: 1.2239x; 1.2239x over previous
//
#include <hip/hip_runtime.h>
#include <hip/hip_bf16.h>
#include <stdint.h>

typedef unsigned short u16;
typedef unsigned int   u32;
typedef unsigned long long u64;
typedef __attribute__((ext_vector_type(4))) float f32x4;
typedef __attribute__((ext_vector_type(8))) short s16x8;

#define NEG_INF (-1e9f)

__device__ __forceinline__ u16 f2bf(float f) {
  __hip_bfloat16 h = __float2bfloat16(f);
  return __builtin_bit_cast(u16, h);
}

__device__ __forceinline__ f32x4 mfma16(s16x8 a, s16x8 b, f32x4 c) {
  return __builtin_amdgcn_mfma_f32_16x16x32_bf16(a, b, c, 0, 0, 0);
}

// async global->LDS, 16 B per lane; LDS dest is wave-uniform base + lane*16
#define GLOAD16(g, l)                                                        \
  __builtin_amdgcn_global_load_lds(                                          \
      (const __attribute__((address_space(1))) unsigned int*)(g),            \
      (__attribute__((address_space(3))) unsigned int*)(l), 16, 0, 0)

// ---------------------------------------------------------------- mask prep
__global__ void detect_mask_kernel(const u32* __restrict__ mraw, u32* __restrict__ flag) {
  __shared__ int any;
  if (threadIdx.x == 0) any = 0;
  __syncthreads();
  int loc = 0;
  for (int i = threadIdx.x; i < 16384; i += 256) {
    u32 v = mraw[i];
    if (v & 0xFFFFFF00u) loc = 1;  // int32 0/1 values never set high bytes
  }
  if (loc) atomicOr(&any, 1);
  __syncthreads();
  if (threadIdx.x == 0) *flag = any ? 1u : 4u;
}

__global__ __launch_bounds__(256) void maskprep_kernel(const void* __restrict__ mraw,
                                                       const u32* __restrict__ flag,
                                                       unsigned char* __restrict__ mb) {
  long long idx = (long long)blockIdx.x * 256 + threadIdx.x;  // B*T*64 = 2097152
  long long bt = idx >> 6;
  int ch = (int)(idx & 63);
  unsigned char byte = 0;
  if (*flag == 1) {
    u64 v = *(const u64*)((const unsigned char*)mraw + bt * 512 + ch * 8);
#pragma unroll
    for (int i = 0; i < 8; i++)
      if ((v >> (8 * i)) & 0xFFull) byte |= (unsigned char)(1 << i);
  } else {
    const int* p = (const int*)mraw + bt * 512 + ch * 8;
#pragma unroll
    for (int i = 0; i < 8; i++)
      if (p[i]) byte |= (unsigned char)(1 << i);
  }
  mb[idx] = byte;
}

// ---------------------------------------------------------------- weight prep
__global__ void transpose_cvt_kernel(const float* __restrict__ in, int ld_in, int off,
                                     int kreal, int CO, u16* __restrict__ outp) {
  int i = blockIdx.x;
  for (int j = threadIdx.x; j < CO; j += 256) {
    float v = (j < kreal) ? in[(long long)j * ld_in + off + i] : 0.0f;
    outp[(long long)i * CO + j] = f2bf(v);
  }
}

__global__ void slice_cvt_kernel(const float* __restrict__ in, u16* __restrict__ outp) {
  long long idx = (long long)blockIdx.x * 256 + threadIdx.x;  // 262144
  long long dd = idx >> 9;
  int hh = (int)(idx & 511);
  outp[idx] = f2bf(in[dd * 1536 + 1024 + hh]);
}

// ------------------------------------------- emb fp32 -> bf16 + partial mean (fused)
__global__ __launch_bounds__(256) void cvt_pmean_kernel(const float* __restrict__ emb,
                                                        u16* __restrict__ ebf,
                                                        float* __restrict__ pmean) {
  const int bq = blockIdx.x >> 2, nq = blockIdx.x & 3;
  const int tid = threadIdx.x;
  const int ro = tid >> 7;            // 0..1 row parity
  const int c4 = (tid & 127) << 2;    // col offset
  const long long base = ((long long)bq * 512 + nq * 128) * 512;
  float s[4] = {0.f, 0.f, 0.f, 0.f};
  for (int n = ro; n < 128; n += 2) {
    f32x4 v = *(const f32x4*)&emb[base + (long long)n * 512 + c4];
    u16 pk[4];
#pragma unroll
    for (int i = 0; i < 4; i++) { s[i] += v[i]; pk[i] = f2bf(v[i]); }
    *(u64*)&ebf[base + (long long)n * 512 + c4] =
        (u64)pk[0] | ((u64)pk[1] << 16) | ((u64)pk[2] << 32) | ((u64)pk[3] << 48);
  }
  __shared__ float ls[2][512];
#pragma unroll
  for (int i = 0; i < 4; i++) ls[ro][c4 + i] = s[i];
  __syncthreads();
  float* dst = pmean + (long long)blockIdx.x * 512;
  dst[tid] = ls[0][tid] + ls[1][tid];
  dst[tid + 256] = ls[0][tid + 256] + ls[1][tid + 256];
}

__global__ __launch_bounds__(256) void fixedctx_kernel(const float* __restrict__ pmean,
                                                       const float* __restrict__ Wc,
                                                       float* __restrict__ fixedc) {
  __shared__ float mf[512];
  int b = blockIdx.x;
  const float* p = pmean + (long long)b * 4 * 512;
  for (int d = threadIdx.x; d < 512; d += 256)
    mf[d] = (p[d] + p[512 + d] + p[1024 + d] + p[1536 + d]) * (1.0f / 512.0f);
  __syncthreads();
  for (int h = threadIdx.x; h < 512; h += 256) {
    float s = 0.f;
    for (int d = 0; d < 512; ++d) s += mf[d] * Wc[(long long)d * 512 + h];
    fixedc[(long long)b * 512 + h] = s;
  }
}

// ---------------------------------------------------------------- next-node features
// nextn[b*128+t][0..511] = ebf[b, cur[b,t], :]; [512..514] = scalars; [515..543] = 0
__global__ __launch_bounds__(256) void build_nextn_kernel(
    const u16* __restrict__ ebf, const int* __restrict__ cur,
    const float* __restrict__ ucap, const float* __restrict__ ubat,
    const float* __restrict__ ctim, u16* __restrict__ outp) {
  const long long rowm = (long long)blockIdx.x * 4 + (threadIdx.x >> 6);
  const int lane = threadIdx.x & 63;
  const int b = (int)(rowm >> 7);
  const int node = cur[rowm];
  const u16* src = ebf + ((long long)b * 512 + node) * 512;
  u16* dst = outp + rowm * 544;
  *(s16x8*)&dst[lane * 8] = *(const s16x8*)&src[lane * 8];
  if (lane < 32) {
    const int c = 512 + lane;
    float v = (lane == 0) ? 1.0f - ucap[rowm]
            : (lane == 1) ? 1.0f - ubat[rowm]
            : (lane == 2) ? ctim[rowm] : 0.0f;
    dst[c] = f2bf(v);
  }
}

// -------------------------------- 128^2 MFMA GEMM, global_load_lds staging (m97 structure)
// C[m][n] = sum_k A[m][k] * B[n][k], both bf16 row-major with K contiguous.
// 1D grid with XCD-chunked swizzle; nx = tiles along n.
// EPI: 0 = scatter to Kbuf/Vtbuf, 1 = +fixed_context -> query bf16,
//      2 = plain bf16 [m][512],  3 = logits: scale/tanh/mask -> f32 d_out
template <int EPI, int BATCHB>
__global__ __launch_bounds__(256) void gemm128_kernel(
    const u16* __restrict__ A, const u16* __restrict__ Bv,
    int ldA, int ldB, int K, int nx, long long strideB,
    void* __restrict__ out0, void* __restrict__ out1, const void* __restrict__ aux) {
  __shared__ u16 lA[128 * 32];
  __shared__ u16 lB[128 * 32];
  const int tid = threadIdx.x;
  const int lane = tid & 63;
  const int wave = tid >> 6;
  const int wr = wave >> 1, wc = wave & 1;

  // XCD-chunked bijective swizzle (gridDim.x % 8 == 0 for all call sites)
  const int p = blockIdx.x;
  const int chunk = (int)(gridDim.x >> 3);
  const int wk = (p & 7) * chunk + (p >> 3);
  const int ntile = wk % nx;
  const int mtile = wk / nx;

  const long long arow0 = (long long)mtile * 128;
  const long long brow0 = (long long)ntile * 128;
  const u16* Bb = Bv + (BATCHB ? (long long)mtile * strideB : 0);

  f32x4 acc[4][4];
#pragma unroll
  for (int i = 0; i < 4; i++)
#pragma unroll
    for (int j = 0; j < 4; j++) acc[i][j] = (f32x4){0.f, 0.f, 0.f, 0.f};

  const int srow = wave * 16 + (lane >> 2);   // staging row within 64-row half
  const int sc8 = (lane & 3) << 3;            // staging k-offset (elements)

  for (int k0 = 0; k0 < K; k0 += 32) {
    __syncthreads();
#pragma unroll
    for (int i = 0; i < 2; i++) {
      GLOAD16(A + (arow0 + i * 64 + srow) * (long long)ldA + k0 + sc8,
              &lA[(i * 64 + wave * 16) * 32]);
      GLOAD16(Bb + (brow0 + i * 64 + srow) * (long long)ldB + k0 + sc8,
              &lB[(i * 64 + wave * 16) * 32]);
    }
    __syncthreads();
    s16x8 af[4], bfr[4];
#pragma unroll
    for (int i = 0; i < 4; i++)
      af[i] = *(const s16x8*)&lA[(wr * 64 + i * 16 + (lane & 15)) * 32 + ((lane >> 4) << 3)];
#pragma unroll
    for (int j = 0; j < 4; j++)
      bfr[j] = *(const s16x8*)&lB[(wc * 64 + j * 16 + (lane & 15)) * 32 + ((lane >> 4) << 3)];
#pragma unroll
    for (int i = 0; i < 4; i++)
#pragma unroll
      for (int j = 0; j < 4; j++) acc[i][j] = mfma16(af[i], bfr[j], acc[i][j]);
  }

  // epilogue: (row, col) = (arow0 + wr*64+i*16+(lane>>4)*4+q, brow0 + wc*64+j*16+(lane&15))
  const float rs512 = 0.044194173824159216f;  // 1/sqrt(512)
#pragma unroll
  for (int i = 0; i < 4; i++) {
    const int rl = wr * 64 + i * 16 + ((lane >> 4) << 2);
#pragma unroll
    for (int j = 0; j < 4; j++) {
      const int cl = wc * 64 + j * 16 + (lane & 15);
      const long long col = brow0 + cl;
#pragma unroll
      for (int q = 0; q < 4; q++) {
        const long long row = arow0 + rl + q;
        float v = acc[i][j][q];
        if (EPI == 0) {
          const int bb = (int)(row >> 9);
          const int node = (int)(row & 511);
          const int part = (int)(col >> 9);
          const int hh = (int)((col >> 6) & 7);
          const int kk = (int)(col & 63);
          if (part == 0)
            ((u16*)out0)[(((long long)(bb * 8 + hh) * 512 + node) << 6) + kk] = f2bf(v);
          else
            ((u16*)out1)[(((long long)(bb * 8 + hh) * 64 + kk) << 9) + node] = f2bf(v);
        } else if (EPI == 1) {
          const float* fc = (const float*)aux;
          const int bb = (int)(row >> 7);
          ((u16*)out0)[row * 512 + col] = f2bf(v + fc[(long long)bb * 512 + col]);
        } else if (EPI == 2) {
          ((u16*)out0)[row * 512 + col] = f2bf(v);
        } else {
          const unsigned char* mb = (const unsigned char*)aux;
          const int bb = (int)(row >> 7);
          const int tt = (int)(row & 127);
          float x = v * rs512;
          float e = exp2f(x * 2.8853900817779268f);  // 2*log2(e)
          float th = 1.0f - 2.0f * __builtin_amdgcn_rcpf(e + 1.0f);
          float lg = 10.0f * th;
          u64 w = ((const u64*)mb)[((long long)(bb * 128 + tt)) * 8 + (col >> 6)];
          if ((w >> (col & 63)) & 1ull) lg = NEG_INF;
          ((float*)out0)[row * 512 + col] = lg;
        }
      }
    }
  }
}

// ---------------------------------------------------------------- fused attention
__global__ __launch_bounds__(256) void attn_kernel(
    const u16* __restrict__ query, const u16* __restrict__ Kbuf,
    const u16* __restrict__ Vtbuf, const u64* __restrict__ maskbits,
    u16* __restrict__ headsout) {
  const int p = blockIdx.x;
  const int fb = (p & 7) * 1024 + (p >> 3);  // XCD-chunked: t-tiles of one (b,h) co-locate
  const int tt = fb & 3;
  const int h = (fb >> 2) & 7;
  const int b = fb >> 5;
  const int tid = threadIdx.x;
  const int lane = tid & 63;
  const int wave = tid >> 6;

  __shared__ u16 P[32 * 512];     // 32 KB, swizzled: byte = t*1024 + ((n*2) ^ ((t&7)<<4))
  __shared__ u64 mrows[32 * 8];
  __shared__ float rsw[4][32];
  __shared__ float rst[32];

  {
    int t = tid >> 3, w = tid & 7;
    mrows[tid] = maskbits[(((long long)b * 128) + tt * 32 + t) * 8 + w];
  }

  const u16* Qb = query + ((long long)(b * 128 + tt * 32)) * 512 + h * 64;
  s16x8 qf[2][2];
#pragma unroll
  for (int tf = 0; tf < 2; tf++)
#pragma unroll
    for (int ks = 0; ks < 2; ks++)
      qf[tf][ks] = *(const s16x8*)(Qb + (long long)(tf * 16 + (lane & 15)) * 512 +
                                   ks * 32 + ((lane >> 4) << 3));

  const int ns = wave * 128;
  const u16* Kb = Kbuf + ((long long)(b * 8 + h) * 512) * 64;
  f32x4 s[8][2];
#pragma unroll
  for (int nf = 0; nf < 8; nf++)
#pragma unroll
    for (int tf = 0; tf < 2; tf++) s[nf][tf] = (f32x4){0.f, 0.f, 0.f, 0.f};
#pragma unroll
  for (int nf = 0; nf < 8; nf++) {
#pragma unroll
    for (int ks = 0; ks < 2; ks++) {
      s16x8 kf = *(const s16x8*)(Kb + (long long)(ns + nf * 16 + (lane & 15)) * 64 +
                                 ks * 32 + ((lane >> 4) << 3));
#pragma unroll
      for (int tf = 0; tf < 2; tf++) s[nf][tf] = mfma16(kf, qf[tf][ks], s[nf][tf]);
    }
  }
  __syncthreads();

  const float CE = 0.18033688011112043f;  // (1/8) * log2(e)
  const int tcol = lane & 15;
  float psum[2] = {0.f, 0.f};
#pragma unroll
  for (int nf = 0; nf < 8; nf++) {
#pragma unroll
    for (int tf = 0; tf < 2; tf++) {
      const int trow = tf * 16 + tcol;
      const u64 w0 = mrows[trow * 8 + wave * 2];
      const u64 w1 = mrows[trow * 8 + wave * 2 + 1];
      u16 pk[4];
#pragma unroll
      for (int q = 0; q < 4; q++) {
        const int nl = nf * 16 + ((lane >> 4) << 2) + q;
        const u64 w = (nl & 64) ? w1 : w0;
        float pv = exp2f(s[nf][tf][q] * CE);
        if ((w >> (nl & 63)) & 1ull) pv = 0.0f;
        psum[tf] += pv;
        pk[q] = f2bf(pv);
      }
      const int nb = (ns + nf * 16 + ((lane >> 4) << 2)) * 2;
      const int off = trow * 1024 + (nb ^ ((trow & 7) << 4));
      u64 pd = (u64)pk[0] | ((u64)pk[1] << 16) | ((u64)pk[2] << 32) | ((u64)pk[3] << 48);
      *(u64*)((char*)P + off) = pd;
    }
  }
#pragma unroll
  for (int tf = 0; tf < 2; tf++) {
    float v = psum[tf];
    v += __shfl_xor(v, 16);
    v += __shfl_xor(v, 32);
    if ((lane >> 4) == 0) rsw[wave][tf * 16 + tcol] = v;
  }
  __syncthreads();
  if (tid < 32) rst[tid] = rsw[0][tid] + rsw[1][tid] + rsw[2][tid] + rsw[3][tid];
  __syncthreads();

  const u16* Vb = Vtbuf + ((long long)(b * 8 + h) * 64 + wave * 16) * 512;
  f32x4 o[2];
  o[0] = (f32x4){0.f, 0.f, 0.f, 0.f};
  o[1] = (f32x4){0.f, 0.f, 0.f, 0.f};
#pragma unroll
  for (int ksn = 0; ksn < 16; ksn++) {
    s16x8 vf = *(const s16x8*)(Vb + (long long)(lane & 15) * 512 + ksn * 32 + ((lane >> 4) << 3));
#pragma unroll
    for (int mf = 0; mf < 2; mf++) {
      const int trow = mf * 16 + (lane & 15);
      const int nb = (ksn * 32 + ((lane >> 4) << 3)) * 2;
      s16x8 pf = *(const s16x8*)((char*)P + trow * 1024 + (nb ^ ((trow & 7) << 4)));
      o[mf] = mfma16(pf, vf, o[mf]);
    }
  }

#pragma unroll
  for (int mf = 0; mf < 2; mf++) {
#pragma unroll
    for (int q = 0; q < 4; q++) {
      const int t = mf * 16 + ((lane >> 4) << 2) + q;
      const float ov = o[mf][q] * __builtin_amdgcn_rcpf(rst[t]);
      const long long row = (long long)b * 128 + tt * 32 + t;
      headsout[row * 512 + h * 64 + wave * 16 + (lane & 15)] = f2bf(ov);
    }
  }
}

// ---------------------------------------------------------------- log-softmax (in-place, row=512)
__global__ __launch_bounds__(256) void logsoftmax_kernel(float* __restrict__ io) {
  const long long row = (long long)blockIdx.x * 4 + (threadIdx.x >> 6);
  const int lane = threadIdx.x & 63;
  float* p = io + row * 512 + lane * 8;
  f32x4 a = *(const f32x4*)p;
  f32x4 b = *(const f32x4*)(p + 4);
  float mx = a[0];
#pragma unroll
  for (int i = 1; i < 4; i++) mx = fmaxf(mx, a[i]);
#pragma unroll
  for (int i = 0; i < 4; i++) mx = fmaxf(mx, b[i]);
#pragma unroll
  for (int d = 1; d < 64; d <<= 1) mx = fmaxf(mx, __shfl_xor(mx, d));
  const float L2E = 1.4426950408889634f;
  float s = 0.f;
#pragma unroll
  for (int i = 0; i < 4; i++) s += exp2f((a[i] - mx) * L2E);
#pragma unroll
  for (int i = 0; i < 4; i++) s += exp2f((b[i] - mx) * L2E);
#pragma unroll
  for (int d = 1; d < 64; d <<= 1) s += __shfl_xor(s, d);
  const float lse = mx + logf(s);
#pragma unroll
  for (int i = 0; i < 4; i++) a[i] -= lse;
#pragma unroll
  for (int i = 0; i < 4; i++) b[i] -= lse;
  *(f32x4*)p = a;
  *(f32x4*)(p + 4) = b;
}

// ---------------------------------------------------------------- launch
extern "C" void kernel_launch(void* const* d_in, const int* in_sizes, int n_in,
                              void* d_out, int out_size, void* d_ws, size_t ws_size,
                              hipStream_t stream) {
  (void)in_sizes; (void)n_in; (void)out_size; (void)ws_size;
  const float* emb  = (const float*)d_in[0];
  const int*   cur  = (const int*)d_in[1];
  const float* ucap = (const float*)d_in[2];
  const float* ubat = (const float*)d_in[3];
  const float* ctim = (const float*)d_in[4];
  const void*  mask = d_in[5];
  const float* Wc   = (const float*)d_in[6];
  const float* Wkvl = (const float*)d_in[7];
  const float* Wstep= (const float*)d_in[8];
  const float* Wout = (const float*)d_in[9];

  char* w = (char*)d_ws;
  size_t off = 0;
  auto take = [&](size_t nbytes) -> char* {
    char* p = w + off;
    off += (nbytes + 255) & ~(size_t)255;
    return p;
  };
  u32* flag            = (u32*)take(4);
  unsigned char* maskb = (unsigned char*)take((size_t)256 * 128 * 64);   // 2 MB
  u16* ebf             = (u16*)take((size_t)256 * 512 * 512 * 2);        // 134 MB bf16 emb
  u16* WkT             = (u16*)take((size_t)1024 * 512 * 2);
  u16* WstepT          = (u16*)take((size_t)512 * 544 * 2);
  u16* WoutT           = (u16*)take((size_t)512 * 512 * 2);
  u16* W2bf            = (u16*)take((size_t)512 * 512 * 2);
  float* pmean         = (float*)take((size_t)1024 * 512 * 4);
  float* fixedc        = (float*)take((size_t)256 * 512 * 4);
  u16* Kbuf            = (u16*)take((size_t)256 * 8 * 512 * 64 * 2);     // 134 MB
  u16* Vtbuf           = (u16*)take((size_t)256 * 8 * 64 * 512 * 2);     // 134 MB
  u16* slotA           = (u16*)take((size_t)32768 * 544 * 2);            // 35.7 MB
  u16* slotB           = (u16*)take((size_t)32768 * 512 * 2);            // 33.6 MB
  u16* nextn = slotA;      // alias chain: nextn -> headsout -> tmp
  u16* query = slotB;      // alias chain: query -> glimpse
  u16* headsout = slotA;
  u16* glimpse = slotB;
  u16* tmpb = slotA;

  detect_mask_kernel<<<1, 256, 0, stream>>>((const u32*)mask, flag);
  maskprep_kernel<<<8192, 256, 0, stream>>>(mask, flag, maskb);
  transpose_cvt_kernel<<<1024, 256, 0, stream>>>(Wkvl, 1536, 0, 512, 512, WkT);
  transpose_cvt_kernel<<<512, 256, 0, stream>>>(Wstep, 512, 0, 515, 544, WstepT);
  transpose_cvt_kernel<<<512, 256, 0, stream>>>(Wout, 512, 0, 512, 512, WoutT);
  slice_cvt_kernel<<<1024, 256, 0, stream>>>(Wkvl, W2bf);
  cvt_pmean_kernel<<<1024, 256, 0, stream>>>(emb, ebf, pmean);
  fixedctx_kernel<<<256, 256, 0, stream>>>(pmean, Wc, fixedc);
  build_nextn_kernel<<<8192, 256, 0, stream>>>(ebf, cur, ucap, ubat, ctim, nextn);

  // KV projection: ebf [131072 x 512] x WkT [1024 x 512] -> Kbuf/Vtbuf (scattered)
  gemm128_kernel<0, 0><<<8192, 256, 0, stream>>>(
      ebf, WkT, 512, 512, 512, 8, 0, Kbuf, Vtbuf, nullptr);
  // query = fixed_context + nextn @ WstepT
  gemm128_kernel<1, 0><<<1024, 256, 0, stream>>>(
      nextn, WstepT, 544, 544, 544, 4, 0, query, nullptr, fixedc);
  // attention
  attn_kernel<<<8192, 256, 0, stream>>>(query, Kbuf, Vtbuf, (const u64*)maskb, headsout);
  // glimpse = headsout @ WoutT
  gemm128_kernel<2, 0><<<1024, 256, 0, stream>>>(
      headsout, WoutT, 512, 512, 512, 4, 0, glimpse, nullptr, nullptr);
  // tmp = glimpse @ W2  (factorized logit_K)
  gemm128_kernel<2, 0><<<1024, 256, 0, stream>>>(
      glimpse, W2bf, 512, 512, 512, 4, 0, tmpb, nullptr, nullptr);
  // logits = tmp @ ebf[b]^T, scaled/tanh/masked -> f32 d_out
  gemm128_kernel<3, 1><<<1024, 256, 0, stream>>>(
      tmpb, ebf, 512, 512, 512, 4, (long long)512 * 512, d_out, nullptr, maskb);
  // in-place log-softmax
  logsoftmax_kernel<<<8192, 256, 0, stream>>>((float*)d_out);
}

// Round 3
// 755.370 us; speedup vs baseline: 1.4265x; 1.1655x over previous
//
#include <hip/hip_runtime.h>
#include <hip/hip_bf16.h>
#include <stdint.h>

typedef unsigned short u16;
typedef unsigned int   u32;
typedef unsigned long long u64;
typedef __attribute__((ext_vector_type(4))) float f32x4;
typedef __attribute__((ext_vector_type(8))) short s16x8;

#define NEG_INF (-1e9f)

__device__ __forceinline__ u16 f2bf(float f) {
  __hip_bfloat16 h = __float2bfloat16(f);
  return __builtin_bit_cast(u16, h);
}

__device__ __forceinline__ f32x4 mfma16(s16x8 a, s16x8 b, f32x4 c) {
  return __builtin_amdgcn_mfma_f32_16x16x32_bf16(a, b, c, 0, 0, 0);
}

// async global->LDS, 16 B per lane; LDS dest is wave-uniform base + lane*16
#define GLOAD16(g, l)                                                        \
  __builtin_amdgcn_global_load_lds(                                          \
      (const __attribute__((address_space(1))) unsigned int*)(g),            \
      (__attribute__((address_space(3))) unsigned int*)(l), 16, 0, 0)

// ---------------------------------------------------------------- mask prep
__global__ void detect_mask_kernel(const u32* __restrict__ mraw, u32* __restrict__ flag) {
  __shared__ int any;
  if (threadIdx.x == 0) any = 0;
  __syncthreads();
  int loc = 0;
  for (int i = threadIdx.x; i < 16384; i += 256) {
    u32 v = mraw[i];
    if (v & 0xFFFFFF00u) loc = 1;  // int32 0/1 values never set high bytes
  }
  if (loc) atomicOr(&any, 1);
  __syncthreads();
  if (threadIdx.x == 0) *flag = any ? 1u : 4u;
}

__global__ __launch_bounds__(256) void maskprep_kernel(const void* __restrict__ mraw,
                                                       const u32* __restrict__ flag,
                                                       unsigned char* __restrict__ mb) {
  long long idx = (long long)blockIdx.x * 256 + threadIdx.x;  // B*T*64 = 2097152
  long long bt = idx >> 6;
  int ch = (int)(idx & 63);
  unsigned char byte = 0;
  if (*flag == 1) {
    u64 v = *(const u64*)((const unsigned char*)mraw + bt * 512 + ch * 8);
#pragma unroll
    for (int i = 0; i < 8; i++)
      if ((v >> (8 * i)) & 0xFFull) byte |= (unsigned char)(1 << i);
  } else {
    const int* p = (const int*)mraw + bt * 512 + ch * 8;
#pragma unroll
    for (int i = 0; i < 8; i++)
      if (p[i]) byte |= (unsigned char)(1 << i);
  }
  mb[idx] = byte;
}

// ---------------------------------------------------------------- weight prep
__global__ void transpose_cvt_kernel(const float* __restrict__ in, int ld_in, int off,
                                     int kreal, int CO, u16* __restrict__ outp) {
  int i = blockIdx.x;
  for (int j = threadIdx.x; j < CO; j += 256) {
    float v = (j < kreal) ? in[(long long)j * ld_in + off + i] : 0.0f;
    outp[(long long)i * CO + j] = f2bf(v);
  }
}

__global__ void slice_cvt_kernel(const float* __restrict__ in, u16* __restrict__ outp) {
  long long idx = (long long)blockIdx.x * 256 + threadIdx.x;  // 262144
  long long dd = idx >> 9;
  int hh = (int)(idx & 511);
  outp[idx] = f2bf(in[dd * 1536 + 1024 + hh]);
}

// ------------------------------------------- emb fp32 -> bf16 + partial mean (fused)
__global__ __launch_bounds__(256) void cvt_pmean_kernel(const float* __restrict__ emb,
                                                        u16* __restrict__ ebf,
                                                        float* __restrict__ pmean) {
  const int bq = blockIdx.x >> 2, nq = blockIdx.x & 3;
  const int tid = threadIdx.x;
  const int ro = tid >> 7;            // 0..1 row parity
  const int c4 = (tid & 127) << 2;    // col offset
  const long long base = ((long long)bq * 512 + nq * 128) * 512;
  float s[4] = {0.f, 0.f, 0.f, 0.f};
  for (int n = ro; n < 128; n += 2) {
    f32x4 v = *(const f32x4*)&emb[base + (long long)n * 512 + c4];
    u16 pk[4];
#pragma unroll
    for (int i = 0; i < 4; i++) { s[i] += v[i]; pk[i] = f2bf(v[i]); }
    *(u64*)&ebf[base + (long long)n * 512 + c4] =
        (u64)pk[0] | ((u64)pk[1] << 16) | ((u64)pk[2] << 32) | ((u64)pk[3] << 48);
  }
  __shared__ float ls[2][512];
#pragma unroll
  for (int i = 0; i < 4; i++) ls[ro][c4 + i] = s[i];
  __syncthreads();
  float* dst = pmean + (long long)blockIdx.x * 512;
  dst[tid] = ls[0][tid] + ls[1][tid];
  dst[tid + 256] = ls[0][tid + 256] + ls[1][tid + 256];
}

__global__ __launch_bounds__(256) void fixedctx_kernel(const float* __restrict__ pmean,
                                                       const float* __restrict__ Wc,
                                                       float* __restrict__ fixedc) {
  __shared__ float mf[512];
  int b = blockIdx.x;
  const float* p = pmean + (long long)b * 4 * 512;
  for (int d = threadIdx.x; d < 512; d += 256)
    mf[d] = (p[d] + p[512 + d] + p[1024 + d] + p[1536 + d]) * (1.0f / 512.0f);
  __syncthreads();
  for (int h = threadIdx.x; h < 512; h += 256) {
    float s = 0.f;
    for (int d = 0; d < 512; ++d) s += mf[d] * Wc[(long long)d * 512 + h];
    fixedc[(long long)b * 512 + h] = s;
  }
}

// ---------------------------------------------------------------- next-node features
__global__ __launch_bounds__(256) void build_nextn_kernel(
    const u16* __restrict__ ebf, const int* __restrict__ cur,
    const float* __restrict__ ucap, const float* __restrict__ ubat,
    const float* __restrict__ ctim, u16* __restrict__ outp) {
  const long long rowm = (long long)blockIdx.x * 4 + (threadIdx.x >> 6);
  const int lane = threadIdx.x & 63;
  const int b = (int)(rowm >> 7);
  const int node = cur[rowm];
  const u16* src = ebf + ((long long)b * 512 + node) * 512;
  u16* dst = outp + rowm * 544;
  *(s16x8*)&dst[lane * 8] = *(const s16x8*)&src[lane * 8];
  if (lane < 32) {
    const int c = 512 + lane;
    float v = (lane == 0) ? 1.0f - ucap[rowm]
            : (lane == 1) ? 1.0f - ubat[rowm]
            : (lane == 2) ? ctim[rowm] : 0.0f;
    dst[c] = f2bf(v);
  }
}

// =============================================================================
// KV projection GEMM: 256x256 tile, BK=64, 8 waves (2Mx4N), phase-split K-loop
// with counted vmcnt (T3+T4), XOR-swizzled LDS (T2), setprio (T5), XCD swizzle.
// C[m][n] = sum_k ebf[m][k] * WkT[n][k]; epilogue scatters to Kbuf/Vtbuf.
// LDS: 2 buffers x (A 32K + B 32K). Buffer d: A at d*65536, B at d*65536+32768;
// each matrix is 2 halves of [128 rows][64 cols] bf16 (16 KB), row stride 128 B.
// Swizzle: physical col-byte = logical ^ ((row&7)<<4); realized on the
// global_load_lds SOURCE address (dest stays linear) and on ds_read addrs.
// =============================================================================
__global__ __launch_bounds__(512, 1) void gemm256_kv_kernel(
    const u16* __restrict__ A, const u16* __restrict__ Bw,
    u16* __restrict__ Kbuf, u16* __restrict__ Vtbuf) {
  __shared__ __align__(16) char lds[131072];
  const int tid = threadIdx.x;
  const int lane = tid & 63;
  const int wid = tid >> 6;
  const int wr = wid >> 2, wc = wid & 3;

  // XCD-chunked swizzle: 2048 blocks, 256/XCD, ntile fastest (A-panel reuse x4)
  const int p = blockIdx.x;
  const int wk = (p & 7) * 256 + (p >> 3);
  const int ntile = wk & 3;
  const int mtile = wk >> 2;
  const long long mrow0 = (long long)mtile * 256;
  const long long nrow0 = (long long)ntile * 256;

  const int rsub = tid >> 3;  // staging row-in-64
  const int ssl = tid & 7;    // staging 16B slot (pre-XOR)

// stage one matrix K-tile (4 x global_load_lds): halves {0,1} x g {0,1}
#define STAGE4(srcb, row0, ldsoff, k0)                                        \
  {                                                                           \
    _Pragma("unroll") for (int hg = 0; hg < 4; hg++) {                        \
      const int half_ = hg >> 1, g_ = hg & 1;                                 \
      const int r_ = half_ * 128 + g_ * 64 + rsub;                            \
      const int colel_ = (k0) + ((ssl ^ (r_ & 7)) << 3);                      \
      GLOAD16((srcb) + ((row0) + r_) * 512ll + colel_,                        \
              lds + (ldsoff) + half_ * 16384 + g_ * 8192 + wid * 1024);       \
    }                                                                         \
  }

  f32x4 acc[8][4];
#pragma unroll
  for (int i = 0; i < 8; i++)
#pragma unroll
    for (int j = 0; j < 4; j++) acc[i][j] = (f32x4){0.f, 0.f, 0.f, 0.f};

  // prologue: tiles 0 and 1 (B then A per tile; 8 loads/wave/tile)
  STAGE4(Bw, nrow0, 32768, 0);
  STAGE4(A, mrow0, 0, 0);
  STAGE4(Bw, nrow0, 65536 + 32768, 64);
  STAGE4(A, mrow0, 65536, 64);

  const int fr = lane & 15;
  const int fq = lane >> 4;
  const int swz = (lane & 7) << 4;

#pragma unroll 1
  for (int t = 0; t < 8; t++) {
    const int d = t & 1;
    // counted vmcnt: allow next tile's 8 loads to stay in flight (T4)
    if (t == 7) asm volatile("s_waitcnt vmcnt(0)" ::: "memory");
    else        asm volatile("s_waitcnt vmcnt(8)" ::: "memory");
    __builtin_amdgcn_s_barrier();          // all waves' tile-t loads landed
    __builtin_amdgcn_sched_barrier(0);

    const char* ab = lds + d * 65536 + wr * 16384;
    const char* bb = lds + d * 65536 + 32768 + (wc >> 1) * 16384;

    // phase 0 reads all 8 B-frags (persist in regs) + A-frags of mb 0,1
    s16x8 bfrag[4][2];
#pragma unroll
    for (int nb = 0; nb < 4; nb++)
#pragma unroll
      for (int ks = 0; ks < 2; ks++) {
        const int brow = (wc & 1) * 64 + nb * 16 + fr;
        bfrag[nb][ks] =
            *(const s16x8*)(bb + brow * 128 + ((ks * 64 + fq * 16) ^ swz));
      }
#pragma unroll
    for (int ph = 0; ph < 4; ph++) {
      s16x8 af[2][2];
#pragma unroll
      for (int mi = 0; mi < 2; mi++)
#pragma unroll
        for (int ks = 0; ks < 2; ks++) {
          const int arow = (ph * 2 + mi) * 16 + fr;
          af[mi][ks] =
              *(const s16x8*)(ab + arow * 128 + ((ks * 64 + fq * 16) ^ swz));
        }
      asm volatile("s_waitcnt lgkmcnt(0)" ::: "memory");
      __builtin_amdgcn_sched_barrier(0);   // rule #18: pin MFMAs below the wait
      __builtin_amdgcn_s_setprio(1);
#pragma unroll
      for (int mi = 0; mi < 2; mi++)
#pragma unroll
        for (int nb = 0; nb < 4; nb++)
#pragma unroll
          for (int ks = 0; ks < 2; ks++)
            acc[ph * 2 + mi][nb] =
                mfma16(af[mi][ks], bfrag[nb][ks], acc[ph * 2 + mi][nb]);
      __builtin_amdgcn_s_setprio(0);
      __builtin_amdgcn_s_barrier();        // phase boundary (role-split for T5)
      __builtin_amdgcn_sched_barrier(0);
      if (ph == 0 && t + 2 < 8) {
        // B region of buf d is dead (frags in regs) -> prefetch B(t+2) now
        STAGE4(Bw, nrow0, d * 65536 + 32768, (t + 2) * 64);
      }
    }
    if (t + 2 < 8) {
      // all waves past phase-3 barrier -> A region of buf d dead
      STAGE4(A, mrow0, d * 65536, (t + 2) * 64);
    }
  }
#undef STAGE4

  // epilogue: row = mrow0 + wr*128 + mb*16 + fq*4 + q ; col = ntile*256 + wc*64 + nb*16 + fr
  const int colbase = (int)(ntile * 256) + wc * 64;
#pragma unroll
  for (int mb = 0; mb < 8; mb++) {
    const long long row = mrow0 + wr * 128 + mb * 16 + fq * 4;
    const int bbx = (int)(row >> 9);
    const int node0 = (int)(row & 511);
#pragma unroll
    for (int nb = 0; nb < 4; nb++) {
      const int col = colbase + nb * 16 + fr;
      const int hh = (col >> 6) & 7;
      const int kk = col & 63;
      if (col < 512) {  // K part: [b,h,node,kk]
        u16* dst = Kbuf + (((long long)(bbx * 8 + hh) * 512 + node0) << 6) + kk;
#pragma unroll
        for (int q = 0; q < 4; q++) dst[(long long)q << 6] = f2bf(acc[mb][nb][q]);
      } else {          // V part: [b,h,kk,node] -- node contiguous in q
        u16 pk[4];
#pragma unroll
        for (int q = 0; q < 4; q++) pk[q] = f2bf(acc[mb][nb][q]);
        *(u64*)(Vtbuf + (((long long)(bbx * 8 + hh) * 64 + kk) << 9) + node0) =
            (u64)pk[0] | ((u64)pk[1] << 16) | ((u64)pk[2] << 32) | ((u64)pk[3] << 48);
      }
    }
  }
}

// -------------------------------- 128^2 MFMA GEMM (m97 structure) for small GEMMs
// EPI: 1 = +fixed_context -> query bf16, 2 = plain bf16 [m][512],
//      3 = logits: scale/tanh/mask -> f32 d_out
template <int EPI, int BATCHB>
__global__ __launch_bounds__(256) void gemm128_kernel(
    const u16* __restrict__ A, const u16* __restrict__ Bv,
    int ldA, int ldB, int K, int nx, long long strideB,
    void* __restrict__ out0, void* __restrict__ out1, const void* __restrict__ aux) {
  __shared__ u16 lA[128 * 32];
  __shared__ u16 lB[128 * 32];
  const int tid = threadIdx.x;
  const int lane = tid & 63;
  const int wave = tid >> 6;
  const int wr = wave >> 1, wc = wave & 1;

  const int p = blockIdx.x;
  const int chunk = (int)(gridDim.x >> 3);
  const int wk = (p & 7) * chunk + (p >> 3);
  const int ntile = wk % nx;
  const int mtile = wk / nx;

  const long long arow0 = (long long)mtile * 128;
  const long long brow0 = (long long)ntile * 128;
  const u16* Bb = Bv + (BATCHB ? (long long)mtile * strideB : 0);

  f32x4 acc[4][4];
#pragma unroll
  for (int i = 0; i < 4; i++)
#pragma unroll
    for (int j = 0; j < 4; j++) acc[i][j] = (f32x4){0.f, 0.f, 0.f, 0.f};

  const int sc8 = (lane & 3) << 3;

  for (int k0 = 0; k0 < K; k0 += 32) {
    __syncthreads();
#pragma unroll
    for (int i = 0; i < 2; i++) {
      GLOAD16(A + (arow0 + i * 64 + wave * 16 + (lane >> 2)) * (long long)ldA + k0 + sc8,
              &lA[(i * 64 + wave * 16) * 32]);
      GLOAD16(Bb + (brow0 + i * 64 + wave * 16 + (lane >> 2)) * (long long)ldB + k0 + sc8,
              &lB[(i * 64 + wave * 16) * 32]);
    }
    __syncthreads();
    s16x8 af[4], bfr[4];
#pragma unroll
    for (int i = 0; i < 4; i++)
      af[i] = *(const s16x8*)&lA[(wr * 64 + i * 16 + (lane & 15)) * 32 + ((lane >> 4) << 3)];
#pragma unroll
    for (int j = 0; j < 4; j++)
      bfr[j] = *(const s16x8*)&lB[(wc * 64 + j * 16 + (lane & 15)) * 32 + ((lane >> 4) << 3)];
#pragma unroll
    for (int i = 0; i < 4; i++)
#pragma unroll
      for (int j = 0; j < 4; j++) acc[i][j] = mfma16(af[i], bfr[j], acc[i][j]);
  }

  const float rs512 = 0.044194173824159216f;  // 1/sqrt(512)
#pragma unroll
  for (int i = 0; i < 4; i++) {
    const int rl = wr * 64 + i * 16 + ((lane >> 4) << 2);
#pragma unroll
    for (int j = 0; j < 4; j++) {
      const int cl = wc * 64 + j * 16 + (lane & 15);
      const long long col = brow0 + cl;
#pragma unroll
      for (int q = 0; q < 4; q++) {
        const long long row = arow0 + rl + q;
        float v = acc[i][j][q];
        if (EPI == 1) {
          const float* fc = (const float*)aux;
          const int bb = (int)(row >> 7);
          ((u16*)out0)[row * 512 + col] = f2bf(v + fc[(long long)bb * 512 + col]);
        } else if (EPI == 2) {
          ((u16*)out0)[row * 512 + col] = f2bf(v);
        } else {
          const unsigned char* mb = (const unsigned char*)aux;
          const int bb = (int)(row >> 7);
          const int tt = (int)(row & 127);
          float x = v * rs512;
          float e = exp2f(x * 2.8853900817779268f);  // 2*log2(e)
          float th = 1.0f - 2.0f * __builtin_amdgcn_rcpf(e + 1.0f);
          float lg = 10.0f * th;
          u64 w = ((const u64*)mb)[((long long)(bb * 128 + tt)) * 8 + (col >> 6)];
          if ((w >> (col & 63)) & 1ull) lg = NEG_INF;
          ((float*)out0)[row * 512 + col] = lg;
        }
      }
    }
  }
}

// ---------------------------------------------------------------- fused attention
__global__ __launch_bounds__(256) void attn_kernel(
    const u16* __restrict__ query, const u16* __restrict__ Kbuf,
    const u16* __restrict__ Vtbuf, const u64* __restrict__ maskbits,
    u16* __restrict__ headsout) {
  const int p = blockIdx.x;
  const int fb = (p & 7) * 1024 + (p >> 3);
  const int tt = fb & 3;
  const int h = (fb >> 2) & 7;
  const int b = fb >> 5;
  const int tid = threadIdx.x;
  const int lane = tid & 63;
  const int wave = tid >> 6;

  __shared__ u16 P[32 * 512];
  __shared__ u64 mrows[32 * 8];
  __shared__ float rsw[4][32];
  __shared__ float rst[32];

  {
    int t = tid >> 3, w = tid & 7;
    mrows[tid] = maskbits[(((long long)b * 128) + tt * 32 + t) * 8 + w];
  }

  const u16* Qb = query + ((long long)(b * 128 + tt * 32)) * 512 + h * 64;
  s16x8 qf[2][2];
#pragma unroll
  for (int tf = 0; tf < 2; tf++)
#pragma unroll
    for (int ks = 0; ks < 2; ks++)
      qf[tf][ks] = *(const s16x8*)(Qb + (long long)(tf * 16 + (lane & 15)) * 512 +
                                   ks * 32 + ((lane >> 4) << 3));

  const int ns = wave * 128;
  const u16* Kb = Kbuf + ((long long)(b * 8 + h) * 512) * 64;
  f32x4 s[8][2];
#pragma unroll
  for (int nf = 0; nf < 8; nf++)
#pragma unroll
    for (int tf = 0; tf < 2; tf++) s[nf][tf] = (f32x4){0.f, 0.f, 0.f, 0.f};
#pragma unroll
  for (int nf = 0; nf < 8; nf++) {
#pragma unroll
    for (int ks = 0; ks < 2; ks++) {
      s16x8 kf = *(const s16x8*)(Kb + (long long)(ns + nf * 16 + (lane & 15)) * 64 +
                                 ks * 32 + ((lane >> 4) << 3));
#pragma unroll
      for (int tf = 0; tf < 2; tf++) s[nf][tf] = mfma16(kf, qf[tf][ks], s[nf][tf]);
    }
  }
  __syncthreads();

  const float CE = 0.18033688011112043f;  // (1/8) * log2(e)
  const int tcol = lane & 15;
  float psum[2] = {0.f, 0.f};
#pragma unroll
  for (int nf = 0; nf < 8; nf++) {
#pragma unroll
    for (int tf = 0; tf < 2; tf++) {
      const int trow = tf * 16 + tcol;
      const u64 w0 = mrows[trow * 8 + wave * 2];
      const u64 w1 = mrows[trow * 8 + wave * 2 + 1];
      u16 pk[4];
#pragma unroll
      for (int q = 0; q < 4; q++) {
        const int nl = nf * 16 + ((lane >> 4) << 2) + q;
        const u64 w = (nl & 64) ? w1 : w0;
        float pv = exp2f(s[nf][tf][q] * CE);
        if ((w >> (nl & 63)) & 1ull) pv = 0.0f;
        psum[tf] += pv;
        pk[q] = f2bf(pv);
      }
      const int nb = (ns + nf * 16 + ((lane >> 4) << 2)) * 2;
      const int off = trow * 1024 + (nb ^ ((trow & 7) << 4));
      u64 pd = (u64)pk[0] | ((u64)pk[1] << 16) | ((u64)pk[2] << 32) | ((u64)pk[3] << 48);
      *(u64*)((char*)P + off) = pd;
    }
  }
#pragma unroll
  for (int tf = 0; tf < 2; tf++) {
    float v = psum[tf];
    v += __shfl_xor(v, 16);
    v += __shfl_xor(v, 32);
    if ((lane >> 4) == 0) rsw[wave][tf * 16 + tcol] = v;
  }
  __syncthreads();
  if (tid < 32) rst[tid] = rsw[0][tid] + rsw[1][tid] + rsw[2][tid] + rsw[3][tid];
  __syncthreads();

  const u16* Vb = Vtbuf + ((long long)(b * 8 + h) * 64 + wave * 16) * 512;
  f32x4 o[2];
  o[0] = (f32x4){0.f, 0.f, 0.f, 0.f};
  o[1] = (f32x4){0.f, 0.f, 0.f, 0.f};
#pragma unroll
  for (int ksn = 0; ksn < 16; ksn++) {
    s16x8 vf = *(const s16x8*)(Vb + (long long)(lane & 15) * 512 + ksn * 32 + ((lane >> 4) << 3));
#pragma unroll
    for (int mf = 0; mf < 2; mf++) {
      const int trow = mf * 16 + (lane & 15);
      const int nb = (ksn * 32 + ((lane >> 4) << 3)) * 2;
      s16x8 pf = *(const s16x8*)((char*)P + trow * 1024 + (nb ^ ((trow & 7) << 4)));
      o[mf] = mfma16(pf, vf, o[mf]);
    }
  }

#pragma unroll
  for (int mf = 0; mf < 2; mf++) {
#pragma unroll
    for (int q = 0; q < 4; q++) {
      const int t = mf * 16 + ((lane >> 4) << 2) + q;
      const float ov = o[mf][q] * __builtin_amdgcn_rcpf(rst[t]);
      const long long row = (long long)b * 128 + tt * 32 + t;
      headsout[row * 512 + h * 64 + wave * 16 + (lane & 15)] = f2bf(ov);
    }
  }
}

// ---------------------------------------------------------------- log-softmax (in-place, row=512)
__global__ __launch_bounds__(256) void logsoftmax_kernel(float* __restrict__ io) {
  const long long row = (long long)blockIdx.x * 4 + (threadIdx.x >> 6);
  const int lane = threadIdx.x & 63;
  float* p = io + row * 512 + lane * 8;
  f32x4 a = *(const f32x4*)p;
  f32x4 b = *(const f32x4*)(p + 4);
  float mx = a[0];
#pragma unroll
  for (int i = 1; i < 4; i++) mx = fmaxf(mx, a[i]);
#pragma unroll
  for (int i = 0; i < 4; i++) mx = fmaxf(mx, b[i]);
#pragma unroll
  for (int d = 1; d < 64; d <<= 1) mx = fmaxf(mx, __shfl_xor(mx, d));
  const float L2E = 1.4426950408889634f;
  float s = 0.f;
#pragma unroll
  for (int i = 0; i < 4; i++) s += exp2f((a[i] - mx) * L2E);
#pragma unroll
  for (int i = 0; i < 4; i++) s += exp2f((b[i] - mx) * L2E);
#pragma unroll
  for (int d = 1; d < 64; d <<= 1) s += __shfl_xor(s, d);
  const float lse = mx + logf(s);
#pragma unroll
  for (int i = 0; i < 4; i++) a[i] -= lse;
#pragma unroll
  for (int i = 0; i < 4; i++) b[i] -= lse;
  *(f32x4*)p = a;
  *(f32x4*)(p + 4) = b;
}

// ---------------------------------------------------------------- launch
extern "C" void kernel_launch(void* const* d_in, const int* in_sizes, int n_in,
                              void* d_out, int out_size, void* d_ws, size_t ws_size,
                              hipStream_t stream) {
  (void)in_sizes; (void)n_in; (void)out_size; (void)ws_size;
  const float* emb  = (const float*)d_in[0];
  const int*   cur  = (const int*)d_in[1];
  const float* ucap = (const float*)d_in[2];
  const float* ubat = (const float*)d_in[3];
  const float* ctim = (const float*)d_in[4];
  const void*  mask = d_in[5];
  const float* Wc   = (const float*)d_in[6];
  const float* Wkvl = (const float*)d_in[7];
  const float* Wstep= (const float*)d_in[8];
  const float* Wout = (const float*)d_in[9];

  char* w = (char*)d_ws;
  size_t off = 0;
  auto take = [&](size_t nbytes) -> char* {
    char* p = w + off;
    off += (nbytes + 255) & ~(size_t)255;
    return p;
  };
  u32* flag            = (u32*)take(4);
  unsigned char* maskb = (unsigned char*)take((size_t)256 * 128 * 64);   // 2 MB
  u16* ebf             = (u16*)take((size_t)256 * 512 * 512 * 2);        // 134 MB bf16 emb
  u16* WkT             = (u16*)take((size_t)1024 * 512 * 2);
  u16* WstepT          = (u16*)take((size_t)512 * 544 * 2);
  u16* WoutT           = (u16*)take((size_t)512 * 512 * 2);
  u16* W2bf            = (u16*)take((size_t)512 * 512 * 2);
  float* pmean         = (float*)take((size_t)1024 * 512 * 4);
  float* fixedc        = (float*)take((size_t)256 * 512 * 4);
  u16* Kbuf            = (u16*)take((size_t)256 * 8 * 512 * 64 * 2);     // 134 MB
  u16* Vtbuf           = (u16*)take((size_t)256 * 8 * 64 * 512 * 2);     // 134 MB
  u16* slotA           = (u16*)take((size_t)32768 * 544 * 2);            // 35.7 MB
  u16* slotB           = (u16*)take((size_t)32768 * 512 * 2);            // 33.6 MB
  u16* nextn = slotA;      // alias chain: nextn -> headsout -> tmp
  u16* query = slotB;      // alias chain: query -> glimpse
  u16* headsout = slotA;
  u16* glimpse = slotB;
  u16* tmpb = slotA;

  detect_mask_kernel<<<1, 256, 0, stream>>>((const u32*)mask, flag);
  maskprep_kernel<<<8192, 256, 0, stream>>>(mask, flag, maskb);
  transpose_cvt_kernel<<<1024, 256, 0, stream>>>(Wkvl, 1536, 0, 512, 512, WkT);
  transpose_cvt_kernel<<<512, 256, 0, stream>>>(Wstep, 512, 0, 515, 544, WstepT);
  transpose_cvt_kernel<<<512, 256, 0, stream>>>(Wout, 512, 0, 512, 512, WoutT);
  slice_cvt_kernel<<<1024, 256, 0, stream>>>(Wkvl, W2bf);
  cvt_pmean_kernel<<<1024, 256, 0, stream>>>(emb, ebf, pmean);
  fixedctx_kernel<<<256, 256, 0, stream>>>(pmean, Wc, fixedc);
  build_nextn_kernel<<<8192, 256, 0, stream>>>(ebf, cur, ucap, ubat, ctim, nextn);

  // KV projection: ebf [131072 x 512] x WkT [1024 x 512] -> Kbuf/Vtbuf
  gemm256_kv_kernel<<<2048, 512, 0, stream>>>(ebf, WkT, Kbuf, Vtbuf);
  // query = fixed_context + nextn @ WstepT
  gemm128_kernel<1, 0><<<1024, 256, 0, stream>>>(
      nextn, WstepT, 544, 544, 544, 4, 0, query, nullptr, fixedc);
  // attention
  attn_kernel<<<8192, 256, 0, stream>>>(query, Kbuf, Vtbuf, (const u64*)maskb, headsout);
  // glimpse = headsout @ WoutT
  gemm128_kernel<2, 0><<<1024, 256, 0, stream>>>(
      headsout, WoutT, 512, 512, 512, 4, 0, glimpse, nullptr, nullptr);
  // tmp = glimpse @ W2  (factorized logit_K)
  gemm128_kernel<2, 0><<<1024, 256, 0, stream>>>(
      glimpse, W2bf, 512, 512, 512, 4, 0, tmpb, nullptr, nullptr);
  // logits = tmp @ ebf[b]^T, scaled/tanh/masked -> f32 d_out
  gemm128_kernel<3, 1><<<1024, 256, 0, stream>>>(
      tmpb, ebf, 512, 512, 512, 4, (long long)512 * 512, d_out, nullptr, maskb);
  // in-place log-softmax
  logsoftmax_kernel<<<8192, 256, 0, stream>>>((float*)d_out);
}

// Round 4
// 695.336 us; speedup vs baseline: 1.5496x; 1.0863x over previous
//
#include <hip/hip_runtime.h>
#include <hip/hip_bf16.h>
#include <stdint.h>

typedef unsigned short u16;
typedef unsigned int   u32;
typedef unsigned long long u64;
typedef __attribute__((ext_vector_type(4))) float f32x4;
typedef __attribute__((ext_vector_type(8))) short s16x8;

#define NEG_INF (-1e9f)

__device__ __forceinline__ u16 f2bf(float f) {
  __hip_bfloat16 h = __float2bfloat16(f);
  return __builtin_bit_cast(u16, h);
}

__device__ __forceinline__ f32x4 mfma16(s16x8 a, s16x8 b, f32x4 c) {
  return __builtin_amdgcn_mfma_f32_16x16x32_bf16(a, b, c, 0, 0, 0);
}

// async global->LDS, 16 B per lane; LDS dest is wave-uniform base + lane*16
#define GLOAD16(g, l)                                                        \
  __builtin_amdgcn_global_load_lds(                                          \
      (const __attribute__((address_space(1))) unsigned int*)(g),            \
      (__attribute__((address_space(3))) unsigned int*)(l), 16, 0, 0)

// ---------------------------------------------------------------- mask prep
__global__ void detect_mask_kernel(const u32* __restrict__ mraw, u32* __restrict__ flag) {
  __shared__ int any;
  if (threadIdx.x == 0) any = 0;
  __syncthreads();
  int loc = 0;
  for (int i = threadIdx.x; i < 16384; i += 256) {
    u32 v = mraw[i];
    if (v & 0xFFFFFF00u) loc = 1;  // int32 0/1 values never set high bytes
  }
  if (loc) atomicOr(&any, 1);
  __syncthreads();
  if (threadIdx.x == 0) *flag = any ? 1u : 4u;
}

__global__ __launch_bounds__(256) void maskprep_kernel(const void* __restrict__ mraw,
                                                       const u32* __restrict__ flag,
                                                       unsigned char* __restrict__ mb) {
  long long idx = (long long)blockIdx.x * 256 + threadIdx.x;  // B*T*64 = 2097152
  long long bt = idx >> 6;
  int ch = (int)(idx & 63);
  unsigned char byte = 0;
  if (*flag == 1) {
    u64 v = *(const u64*)((const unsigned char*)mraw + bt * 512 + ch * 8);
#pragma unroll
    for (int i = 0; i < 8; i++)
      if ((v >> (8 * i)) & 0xFFull) byte |= (unsigned char)(1 << i);
  } else {
    const int* p = (const int*)mraw + bt * 512 + ch * 8;
#pragma unroll
    for (int i = 0; i < 8; i++)
      if (p[i]) byte |= (unsigned char)(1 << i);
  }
  mb[idx] = byte;
}

// ---------------------------------------------------------------- weight prep
// out[i][j] = (j < kreal ? in[j*ld_in + off + i] : 0), out row-major [RO][CO]
__global__ void transpose_cvt_kernel(const float* __restrict__ in, int ld_in, int off,
                                     int kreal, int CO, u16* __restrict__ outp) {
  int i = blockIdx.x;
  for (int j = threadIdx.x; j < CO; j += 256) {
    float v = (j < kreal) ? in[(long long)j * ld_in + off + i] : 0.0f;
    outp[(long long)i * CO + j] = f2bf(v);
  }
}

__global__ void slice_cvt_kernel(const float* __restrict__ in, u16* __restrict__ outp) {
  long long idx = (long long)blockIdx.x * 256 + threadIdx.x;  // 262144
  long long dd = idx >> 9;
  int hh = (int)(idx & 511);
  outp[idx] = f2bf(in[dd * 1536 + 1024 + hh]);
}

__global__ void cvt_bf_kernel(const float* __restrict__ in, u16* __restrict__ outp) {
  long long idx = (long long)blockIdx.x * 256 + threadIdx.x;
  outp[idx] = f2bf(in[idx]);
}

// ------------------------------------------- emb fp32 -> bf16 + partial mean (fused)
__global__ __launch_bounds__(256) void cvt_pmean_kernel(const float* __restrict__ emb,
                                                        u16* __restrict__ ebf,
                                                        float* __restrict__ pmean) {
  const int bq = blockIdx.x >> 2, nq = blockIdx.x & 3;
  const int tid = threadIdx.x;
  const int ro = tid >> 7;            // 0..1 row parity
  const int c4 = (tid & 127) << 2;    // col offset
  const long long base = ((long long)bq * 512 + nq * 128) * 512;
  float s[4] = {0.f, 0.f, 0.f, 0.f};
  for (int n = ro; n < 128; n += 2) {
    f32x4 v = *(const f32x4*)&emb[base + (long long)n * 512 + c4];
    u16 pk[4];
#pragma unroll
    for (int i = 0; i < 4; i++) { s[i] += v[i]; pk[i] = f2bf(v[i]); }
    *(u64*)&ebf[base + (long long)n * 512 + c4] =
        (u64)pk[0] | ((u64)pk[1] << 16) | ((u64)pk[2] << 32) | ((u64)pk[3] << 48);
  }
  __shared__ float ls[2][512];
#pragma unroll
  for (int i = 0; i < 4; i++) ls[ro][c4 + i] = s[i];
  __syncthreads();
  float* dst = pmean + (long long)blockIdx.x * 512;
  dst[tid] = ls[0][tid] + ls[1][tid];
  dst[tid + 256] = ls[0][tid + 256] + ls[1][tid + 256];
}

__global__ __launch_bounds__(256) void fixedctx_kernel(const float* __restrict__ pmean,
                                                       const float* __restrict__ Wc,
                                                       float* __restrict__ fixedc) {
  __shared__ float mf[512];
  int b = blockIdx.x;
  const float* p = pmean + (long long)b * 4 * 512;
  for (int d = threadIdx.x; d < 512; d += 256)
    mf[d] = (p[d] + p[512 + d] + p[1024 + d] + p[1536 + d]) * (1.0f / 512.0f);
  __syncthreads();
  for (int h = threadIdx.x; h < 512; h += 256) {
    float s = 0.f;
    for (int d = 0; d < 512; ++d) s += mf[d] * Wc[(long long)d * 512 + h];
    fixedc[(long long)b * 512 + h] = s;
  }
}

// ---------------------------------------------------------------- next-node features
// nextn[row][0..511] = ebf[b, cur, :]; [512..514] scalars; [515..575] zero  (ld = 576)
__global__ __launch_bounds__(256) void build_nextn_kernel(
    const u16* __restrict__ ebf, const int* __restrict__ cur,
    const float* __restrict__ ucap, const float* __restrict__ ubat,
    const float* __restrict__ ctim, u16* __restrict__ outp) {
  const long long rowm = (long long)blockIdx.x * 4 + (threadIdx.x >> 6);
  const int lane = threadIdx.x & 63;
  const int b = (int)(rowm >> 7);
  const int node = cur[rowm];
  const u16* src = ebf + ((long long)b * 512 + node) * 512;
  u16* dst = outp + rowm * 576;
  *(s16x8*)&dst[lane * 8] = *(const s16x8*)&src[lane * 8];
  {
    const int c = 512 + lane;
    float v = (lane == 0) ? 1.0f - ucap[rowm]
            : (lane == 1) ? 1.0f - ubat[rowm]
            : (lane == 2) ? ctim[rowm] : 0.0f;
    dst[c] = f2bf(v);
  }
}

// =============================================================================
// KV projection GEMM: 256x256 tile, BK=64, 8 waves (2Mx4N), phase-split K-loop
// with counted vmcnt (T3+T4), XOR-swizzled LDS (T2), setprio (T5), XCD swizzle.
// =============================================================================
__global__ __launch_bounds__(512, 1) void gemm256_kv_kernel(
    const u16* __restrict__ A, const u16* __restrict__ Bw,
    u16* __restrict__ Kbuf, u16* __restrict__ Vtbuf) {
  __shared__ __align__(16) char lds[131072];
  const int tid = threadIdx.x;
  const int lane = tid & 63;
  const int wid = tid >> 6;
  const int wr = wid >> 2, wc = wid & 3;

  const int p = blockIdx.x;
  const int wk = (p & 7) * 256 + (p >> 3);
  const int ntile = wk & 3;
  const int mtile = wk >> 2;
  const long long mrow0 = (long long)mtile * 256;
  const long long nrow0 = (long long)ntile * 256;

  const int rsub = tid >> 3;
  const int ssl = tid & 7;

#define STAGE4(srcb, row0, ldsoff, k0)                                        \
  {                                                                           \
    _Pragma("unroll") for (int hg = 0; hg < 4; hg++) {                        \
      const int half_ = hg >> 1, g_ = hg & 1;                                 \
      const int r_ = half_ * 128 + g_ * 64 + rsub;                            \
      const int colel_ = (k0) + ((ssl ^ (r_ & 7)) << 3);                      \
      GLOAD16((srcb) + ((row0) + r_) * 512ll + colel_,                        \
              lds + (ldsoff) + half_ * 16384 + g_ * 8192 + wid * 1024);       \
    }                                                                         \
  }

  f32x4 acc[8][4];
#pragma unroll
  for (int i = 0; i < 8; i++)
#pragma unroll
    for (int j = 0; j < 4; j++) acc[i][j] = (f32x4){0.f, 0.f, 0.f, 0.f};

  STAGE4(Bw, nrow0, 32768, 0);
  STAGE4(A, mrow0, 0, 0);
  STAGE4(Bw, nrow0, 65536 + 32768, 64);
  STAGE4(A, mrow0, 65536, 64);

  const int fr = lane & 15;
  const int fq = lane >> 4;
  const int swz = (lane & 7) << 4;

#pragma unroll 1
  for (int t = 0; t < 8; t++) {
    const int d = t & 1;
    if (t == 7) asm volatile("s_waitcnt vmcnt(0)" ::: "memory");
    else        asm volatile("s_waitcnt vmcnt(8)" ::: "memory");
    __builtin_amdgcn_s_barrier();
    __builtin_amdgcn_sched_barrier(0);

    const char* ab = lds + d * 65536 + wr * 16384;
    const char* bb = lds + d * 65536 + 32768 + (wc >> 1) * 16384;

    s16x8 bfrag[4][2];
#pragma unroll
    for (int nb = 0; nb < 4; nb++)
#pragma unroll
      for (int ks = 0; ks < 2; ks++) {
        const int brow = (wc & 1) * 64 + nb * 16 + fr;
        bfrag[nb][ks] =
            *(const s16x8*)(bb + brow * 128 + ((ks * 64 + fq * 16) ^ swz));
      }
#pragma unroll
    for (int ph = 0; ph < 4; ph++) {
      s16x8 af[2][2];
#pragma unroll
      for (int mi = 0; mi < 2; mi++)
#pragma unroll
        for (int ks = 0; ks < 2; ks++) {
          const int arow = (ph * 2 + mi) * 16 + fr;
          af[mi][ks] =
              *(const s16x8*)(ab + arow * 128 + ((ks * 64 + fq * 16) ^ swz));
        }
      asm volatile("s_waitcnt lgkmcnt(0)" ::: "memory");
      __builtin_amdgcn_sched_barrier(0);
      __builtin_amdgcn_s_setprio(1);
#pragma unroll
      for (int mi = 0; mi < 2; mi++)
#pragma unroll
        for (int nb = 0; nb < 4; nb++)
#pragma unroll
          for (int ks = 0; ks < 2; ks++)
            acc[ph * 2 + mi][nb] =
                mfma16(af[mi][ks], bfrag[nb][ks], acc[ph * 2 + mi][nb]);
      __builtin_amdgcn_s_setprio(0);
      __builtin_amdgcn_s_barrier();
      __builtin_amdgcn_sched_barrier(0);
      if (ph == 0 && t + 2 < 8) {
        STAGE4(Bw, nrow0, d * 65536 + 32768, (t + 2) * 64);
      }
    }
    if (t + 2 < 8) {
      STAGE4(A, mrow0, d * 65536, (t + 2) * 64);
    }
  }
#undef STAGE4

  const int colbase = (int)(ntile * 256) + wc * 64;
#pragma unroll
  for (int mb = 0; mb < 8; mb++) {
    const long long row = mrow0 + wr * 128 + mb * 16 + fq * 4;
    const int bbx = (int)(row >> 9);
    const int node0 = (int)(row & 511);
#pragma unroll
    for (int nb = 0; nb < 4; nb++) {
      const int col = colbase + nb * 16 + fr;
      const int hh = (col >> 6) & 7;
      const int kk = col & 63;
      if (col < 512) {  // K part: [b,h,node,kk]
        u16* dst = Kbuf + (((long long)(bbx * 8 + hh) * 512 + node0) << 6) + kk;
#pragma unroll
        for (int q = 0; q < 4; q++) dst[(long long)q << 6] = f2bf(acc[mb][nb][q]);
      } else {          // V part: [b,h,kk,node]
        u16 pk[4];
#pragma unroll
        for (int q = 0; q < 4; q++) pk[q] = f2bf(acc[mb][nb][q]);
        *(u64*)(Vtbuf + (((long long)(bbx * 8 + hh) * 64 + kk) << 9) + node0) =
            (u64)pk[0] | ((u64)pk[1] << 16) | ((u64)pk[2] << 32) | ((u64)pk[3] << 48);
      }
    }
  }
}

// =============================================================================
// gemmW: BM=256, BN=128, BK=64, 8 waves (4M x 2N), 8-phase-style schedule with
// counted vmcnt, T2 swizzle, setprio. C[m][n] = sum_k A[m][k]*B[n][k].
// MODE 0: query epilogue (+fixedc, bf16 out ld512), grid = (M/256)*4, N=512
// MODE 1: plain bf16 out ld512, grid = (M/256)*4, N=512
// MODE 2: batched logits-T: per wk: b=wk>>1, mtile=wk&1; A=ebf_b (M=512 nodes),
//         B=tmp_b (N=128 t); out f32 d_out[b,t,node] with tanh+mask epilogue.
// LDS per buffer: A 32K (4 groups of 64 rows x 128B) + B 16K (2 groups) = 48K.
// =============================================================================
template <int MODE>
__global__ __launch_bounds__(512, 1) void gemmW_kernel(
    const u16* __restrict__ A, const u16* __restrict__ Bv,
    int ldA, int ldB, int K,
    void* __restrict__ out0, const void* __restrict__ aux) {
  __shared__ __align__(16) char lds[98304];
  const int tid = threadIdx.x;
  const int lane = tid & 63;
  const int wid = tid >> 6;
  const int wr = wid >> 1, wc = wid & 1;  // 4M x 2N

  const int p = blockIdx.x;
  const int chunk = (int)(gridDim.x >> 3);
  const int wk = (p & 7) * chunk + (p >> 3);
  int mtile, bidx = 0, ntile = 0;
  if (MODE == 2) { bidx = wk >> 1; mtile = wk & 1; }
  else { mtile = wk >> 2; ntile = wk & 3; }
  const long long mrow0 = (long long)mtile * 256;
  const u16* Ab = A + (MODE == 2 ? (long long)bidx * 262144 : 0);
  const u16* Bb = Bv + (MODE == 2 ? (long long)bidx * 65536
                                  : (long long)ntile * 128 * ldB);

  const int rsub = tid >> 3;
  const int ssl = tid & 7;

#define STAGEA(dd, k0)                                                        \
  {                                                                           \
    _Pragma("unroll") for (int g_ = 0; g_ < 4; g_++) {                        \
      const int r_ = g_ * 64 + rsub;                                          \
      const int colel_ = (k0) + ((ssl ^ (r_ & 7)) << 3);                      \
      GLOAD16(Ab + (mrow0 + r_) * (long long)ldA + colel_,                    \
              lds + (dd) * 49152 + g_ * 8192 + wid * 1024);                   \
    }                                                                         \
  }
#define STAGEB(dd, k0)                                                        \
  {                                                                           \
    _Pragma("unroll") for (int g_ = 0; g_ < 2; g_++) {                        \
      const int r_ = g_ * 64 + rsub;                                          \
      const int colel_ = (k0) + ((ssl ^ (r_ & 7)) << 3);                      \
      GLOAD16(Bb + r_ * (long long)ldB + colel_,                              \
              lds + (dd) * 49152 + 32768 + g_ * 8192 + wid * 1024);           \
    }                                                                         \
  }

  f32x4 acc[4][4];
#pragma unroll
  for (int i = 0; i < 4; i++)
#pragma unroll
    for (int j = 0; j < 4; j++) acc[i][j] = (f32x4){0.f, 0.f, 0.f, 0.f};

  STAGEB(0, 0);
  STAGEA(0, 0);
  STAGEB(1, 64);
  STAGEA(1, 64);

  const int fr = lane & 15;
  const int fq = lane >> 4;
  const int swz = (lane & 7) << 4;
  const int NT = K >> 6;

#pragma unroll 1
  for (int t = 0; t < NT; t++) {
    const int d = t & 1;
    if (t == NT - 1) asm volatile("s_waitcnt vmcnt(0)" ::: "memory");
    else             asm volatile("s_waitcnt vmcnt(6)" ::: "memory");
    __builtin_amdgcn_s_barrier();
    __builtin_amdgcn_sched_barrier(0);

    const char* ab = lds + d * 49152 + wr * 8192;
    const char* bb = lds + d * 49152 + 32768 + wc * 8192;

    s16x8 bfrag[4][2];
#pragma unroll
    for (int nb = 0; nb < 4; nb++)
#pragma unroll
      for (int ks = 0; ks < 2; ks++) {
        const int brow = nb * 16 + fr;
        bfrag[nb][ks] =
            *(const s16x8*)(bb + brow * 128 + ((ks * 64 + fq * 16) ^ swz));
      }
#pragma unroll
    for (int ph = 0; ph < 4; ph++) {
      s16x8 af[2];
#pragma unroll
      for (int ks = 0; ks < 2; ks++) {
        const int arow = ph * 16 + fr;
        af[ks] = *(const s16x8*)(ab + arow * 128 + ((ks * 64 + fq * 16) ^ swz));
      }
      asm volatile("s_waitcnt lgkmcnt(0)" ::: "memory");
      __builtin_amdgcn_sched_barrier(0);
      __builtin_amdgcn_s_setprio(1);
#pragma unroll
      for (int nb = 0; nb < 4; nb++)
#pragma unroll
        for (int ks = 0; ks < 2; ks++)
          acc[ph][nb] = mfma16(af[ks], bfrag[nb][ks], acc[ph][nb]);
      __builtin_amdgcn_s_setprio(0);
      __builtin_amdgcn_s_barrier();
      __builtin_amdgcn_sched_barrier(0);
      if (ph == 0 && t + 2 < NT) STAGEB(d, (t + 2) * 64);
    }
    if (t + 2 < NT) STAGEA(d, (t + 2) * 64);
  }
#undef STAGEA
#undef STAGEB

  const float rs512 = 0.044194173824159216f;  // 1/sqrt(512)
  if (MODE == 2) {
#pragma unroll
    for (int mb = 0; mb < 4; mb++) {
      const int node0 = (int)mrow0 + wr * 64 + mb * 16 + fq * 4;
#pragma unroll
      for (int nb = 0; nb < 4; nb++) {
        const int tt = wc * 64 + nb * 16 + fr;
        const long long orow = (long long)bidx * 128 + tt;
        const u64 w = ((const u64*)aux)[orow * 8 + (node0 >> 6)];
        f32x4 r;
#pragma unroll
        for (int q = 0; q < 4; q++) {
          float x = acc[mb][nb][q] * rs512;
          float e = exp2f(x * 2.8853900817779268f);  // 2*log2(e)
          float th = 1.0f - 2.0f * __builtin_amdgcn_rcpf(e + 1.0f);
          float lg = 10.0f * th;
          if ((w >> ((node0 & 63) + q)) & 1ull) lg = NEG_INF;
          r[q] = lg;
        }
        *(f32x4*)&((float*)out0)[orow * 512 + node0] = r;
      }
    }
  } else {
    const int colbase = ntile * 128 + wc * 64;
#pragma unroll
    for (int mb = 0; mb < 4; mb++) {
      const long long row0 = mrow0 + wr * 64 + mb * 16 + fq * 4;
#pragma unroll
      for (int nb = 0; nb < 4; nb++) {
        const int col = colbase + nb * 16 + fr;
#pragma unroll
        for (int q = 0; q < 4; q++) {
          const long long row = row0 + q;
          float v = acc[mb][nb][q];
          if (MODE == 0) {
            const float* fc = (const float*)aux;
            v += fc[(row >> 7) * 512 + col];
          }
          ((u16*)out0)[row * 512 + col] = f2bf(v);
        }
      }
    }
  }
}

// ---------------- small 128^2 GEMM (used once for WfT = W2^T-contract-Wout)
__global__ __launch_bounds__(256) void gemm128_plain_kernel(
    const u16* __restrict__ A, const u16* __restrict__ Bv, u16* __restrict__ outp) {
  __shared__ u16 lA[128 * 32];
  __shared__ u16 lB[128 * 32];
  const int tid = threadIdx.x;
  const int lane = tid & 63;
  const int wave = tid >> 6;
  const int wr = wave >> 1, wc = wave & 1;

  const int p = blockIdx.x;  // grid 16
  const int wk = (p & 7) * 2 + (p >> 3);
  const int ntile = wk & 3;
  const int mtile = wk >> 2;
  const long long arow0 = (long long)mtile * 128;
  const long long brow0 = (long long)ntile * 128;

  f32x4 acc[4][4];
#pragma unroll
  for (int i = 0; i < 4; i++)
#pragma unroll
    for (int j = 0; j < 4; j++) acc[i][j] = (f32x4){0.f, 0.f, 0.f, 0.f};

  const int sc8 = (lane & 3) << 3;

  for (int k0 = 0; k0 < 512; k0 += 32) {
    __syncthreads();
#pragma unroll
    for (int i = 0; i < 2; i++) {
      GLOAD16(A + (arow0 + i * 64 + wave * 16 + (lane >> 2)) * 512ll + k0 + sc8,
              &lA[(i * 64 + wave * 16) * 32]);
      GLOAD16(Bv + (brow0 + i * 64 + wave * 16 + (lane >> 2)) * 512ll + k0 + sc8,
              &lB[(i * 64 + wave * 16) * 32]);
    }
    __syncthreads();
    s16x8 af[4], bfr[4];
#pragma unroll
    for (int i = 0; i < 4; i++)
      af[i] = *(const s16x8*)&lA[(wr * 64 + i * 16 + (lane & 15)) * 32 + ((lane >> 4) << 3)];
#pragma unroll
    for (int j = 0; j < 4; j++)
      bfr[j] = *(const s16x8*)&lB[(wc * 64 + j * 16 + (lane & 15)) * 32 + ((lane >> 4) << 3)];
#pragma unroll
    for (int i = 0; i < 4; i++)
#pragma unroll
      for (int j = 0; j < 4; j++) acc[i][j] = mfma16(af[i], bfr[j], acc[i][j]);
  }

#pragma unroll
  for (int i = 0; i < 4; i++) {
    const int rl = wr * 64 + i * 16 + ((lane >> 4) << 2);
#pragma unroll
    for (int j = 0; j < 4; j++) {
      const int cl = wc * 64 + j * 16 + (lane & 15);
#pragma unroll
      for (int q = 0; q < 4; q++)
        outp[(arow0 + rl + q) * 512 + brow0 + cl] = f2bf(acc[i][j][q]);
    }
  }
}

// ---------------------------------------------------------------- fused attention
__global__ __launch_bounds__(256) void attn_kernel(
    const u16* __restrict__ query, const u16* __restrict__ Kbuf,
    const u16* __restrict__ Vtbuf, const u64* __restrict__ maskbits,
    u16* __restrict__ headsout) {
  const int p = blockIdx.x;
  const int fb = (p & 7) * 1024 + (p >> 3);
  const int tt = fb & 3;
  const int h = (fb >> 2) & 7;
  const int b = fb >> 5;
  const int tid = threadIdx.x;
  const int lane = tid & 63;
  const int wave = tid >> 6;

  __shared__ u16 P[32 * 512];
  __shared__ u64 mrows[32 * 8];
  __shared__ float rsw[4][32];
  __shared__ float rst[32];

  {
    int t = tid >> 3, w = tid & 7;
    mrows[tid] = maskbits[(((long long)b * 128) + tt * 32 + t) * 8 + w];
  }

  const u16* Qb = query + ((long long)(b * 128 + tt * 32)) * 512 + h * 64;
  s16x8 qf[2][2];
#pragma unroll
  for (int tf = 0; tf < 2; tf++)
#pragma unroll
    for (int ks = 0; ks < 2; ks++)
      qf[tf][ks] = *(const s16x8*)(Qb + (long long)(tf * 16 + (lane & 15)) * 512 +
                                   ks * 32 + ((lane >> 4) << 3));

  const int ns = wave * 128;
  const u16* Kb = Kbuf + ((long long)(b * 8 + h) * 512) * 64;
  f32x4 s[8][2];
#pragma unroll
  for (int nf = 0; nf < 8; nf++)
#pragma unroll
    for (int tf = 0; tf < 2; tf++) s[nf][tf] = (f32x4){0.f, 0.f, 0.f, 0.f};
#pragma unroll
  for (int nf = 0; nf < 8; nf++) {
#pragma unroll
    for (int ks = 0; ks < 2; ks++) {
      s16x8 kf = *(const s16x8*)(Kb + (long long)(ns + nf * 16 + (lane & 15)) * 64 +
                                 ks * 32 + ((lane >> 4) << 3));
#pragma unroll
      for (int tf = 0; tf < 2; tf++) s[nf][tf] = mfma16(kf, qf[tf][ks], s[nf][tf]);
    }
  }
  __syncthreads();

  const float CE = 0.18033688011112043f;  // (1/8) * log2(e)
  const int tcol = lane & 15;
  float psum[2] = {0.f, 0.f};
#pragma unroll
  for (int nf = 0; nf < 8; nf++) {
#pragma unroll
    for (int tf = 0; tf < 2; tf++) {
      const int trow = tf * 16 + tcol;
      const u64 w0 = mrows[trow * 8 + wave * 2];
      const u64 w1 = mrows[trow * 8 + wave * 2 + 1];
      u16 pk[4];
#pragma unroll
      for (int q = 0; q < 4; q++) {
        const int nl = nf * 16 + ((lane >> 4) << 2) + q;
        const u64 w = (nl & 64) ? w1 : w0;
        float pv = exp2f(s[nf][tf][q] * CE);
        if ((w >> (nl & 63)) & 1ull) pv = 0.0f;
        psum[tf] += pv;
        pk[q] = f2bf(pv);
      }
      const int nb = (ns + nf * 16 + ((lane >> 4) << 2)) * 2;
      const int off = trow * 1024 + (nb ^ ((trow & 7) << 4));
      u64 pd = (u64)pk[0] | ((u64)pk[1] << 16) | ((u64)pk[2] << 32) | ((u64)pk[3] << 48);
      *(u64*)((char*)P + off) = pd;
    }
  }
#pragma unroll
  for (int tf = 0; tf < 2; tf++) {
    float v = psum[tf];
    v += __shfl_xor(v, 16);
    v += __shfl_xor(v, 32);
    if ((lane >> 4) == 0) rsw[wave][tf * 16 + tcol] = v;
  }
  __syncthreads();
  if (tid < 32) rst[tid] = rsw[0][tid] + rsw[1][tid] + rsw[2][tid] + rsw[3][tid];
  __syncthreads();

  const u16* Vb = Vtbuf + ((long long)(b * 8 + h) * 64 + wave * 16) * 512;
  f32x4 o[2];
  o[0] = (f32x4){0.f, 0.f, 0.f, 0.f};
  o[1] = (f32x4){0.f, 0.f, 0.f, 0.f};
#pragma unroll
  for (int ksn = 0; ksn < 16; ksn++) {
    s16x8 vf = *(const s16x8*)(Vb + (long long)(lane & 15) * 512 + ksn * 32 + ((lane >> 4) << 3));
#pragma unroll
    for (int mf = 0; mf < 2; mf++) {
      const int trow = mf * 16 + (lane & 15);
      const int nb = (ksn * 32 + ((lane >> 4) << 3)) * 2;
      s16x8 pf = *(const s16x8*)((char*)P + trow * 1024 + (nb ^ ((trow & 7) << 4)));
      o[mf] = mfma16(pf, vf, o[mf]);
    }
  }

#pragma unroll
  for (int mf = 0; mf < 2; mf++) {
#pragma unroll
    for (int q = 0; q < 4; q++) {
      const int t = mf * 16 + ((lane >> 4) << 2) + q;
      const float ov = o[mf][q] * __builtin_amdgcn_rcpf(rst[t]);
      const long long row = (long long)b * 128 + tt * 32 + t;
      headsout[row * 512 + h * 64 + wave * 16 + (lane & 15)] = f2bf(ov);
    }
  }
}

// ---------------------------------------------------------------- log-softmax (in-place, row=512)
__global__ __launch_bounds__(256) void logsoftmax_kernel(float* __restrict__ io) {
  const long long row = (long long)blockIdx.x * 4 + (threadIdx.x >> 6);
  const int lane = threadIdx.x & 63;
  float* p = io + row * 512 + lane * 8;
  f32x4 a = *(const f32x4*)p;
  f32x4 b = *(const f32x4*)(p + 4);
  float mx = a[0];
#pragma unroll
  for (int i = 1; i < 4; i++) mx = fmaxf(mx, a[i]);
#pragma unroll
  for (int i = 0; i < 4; i++) mx = fmaxf(mx, b[i]);
#pragma unroll
  for (int d = 1; d < 64; d <<= 1) mx = fmaxf(mx, __shfl_xor(mx, d));
  const float L2E = 1.4426950408889634f;
  float s = 0.f;
#pragma unroll
  for (int i = 0; i < 4; i++) s += exp2f((a[i] - mx) * L2E);
#pragma unroll
  for (int i = 0; i < 4; i++) s += exp2f((b[i] - mx) * L2E);
#pragma unroll
  for (int d = 1; d < 64; d <<= 1) s += __shfl_xor(s, d);
  const float lse = mx + logf(s);
#pragma unroll
  for (int i = 0; i < 4; i++) a[i] -= lse;
#pragma unroll
  for (int i = 0; i < 4; i++) b[i] -= lse;
  *(f32x4*)p = a;
  *(f32x4*)(p + 4) = b;
}

// ---------------------------------------------------------------- launch
extern "C" void kernel_launch(void* const* d_in, const int* in_sizes, int n_in,
                              void* d_out, int out_size, void* d_ws, size_t ws_size,
                              hipStream_t stream) {
  (void)in_sizes; (void)n_in; (void)out_size; (void)ws_size;
  const float* emb  = (const float*)d_in[0];
  const int*   cur  = (const int*)d_in[1];
  const float* ucap = (const float*)d_in[2];
  const float* ubat = (const float*)d_in[3];
  const float* ctim = (const float*)d_in[4];
  const void*  mask = d_in[5];
  const float* Wc   = (const float*)d_in[6];
  const float* Wkvl = (const float*)d_in[7];
  const float* Wstep= (const float*)d_in[8];
  const float* Wout = (const float*)d_in[9];

  char* w = (char*)d_ws;
  size_t off = 0;
  auto take = [&](size_t nbytes) -> char* {
    char* p = w + off;
    off += (nbytes + 255) & ~(size_t)255;
    return p;
  };
  u32* flag            = (u32*)take(4);
  unsigned char* maskb = (unsigned char*)take((size_t)256 * 128 * 64);   // 2 MB
  u16* ebf             = (u16*)take((size_t)256 * 512 * 512 * 2);        // 134 MB
  u16* WstepT          = (u16*)take((size_t)512 * 576 * 2);
  u16* W2bf            = (u16*)take((size_t)512 * 512 * 2);
  u16* Woutbf          = (u16*)take((size_t)512 * 512 * 2);
  u16* WfT             = (u16*)take((size_t)512 * 512 * 2);
  float* pmean         = (float*)take((size_t)1024 * 512 * 4);
  float* fixedc        = (float*)take((size_t)256 * 512 * 4);
  u16* Kbuf            = (u16*)take((size_t)256 * 8 * 512 * 64 * 2);     // 134 MB
  u16* Vtbuf           = (u16*)take((size_t)256 * 8 * 64 * 512 * 2);     // 134 MB
  u16* slotA           = (u16*)take((size_t)32768 * 576 * 2);            // 37.7 MB
  u16* slotB           = (u16*)take((size_t)32768 * 512 * 2);            // 33.6 MB
  u16* nextn = slotA;      // alias chain: nextn -> headsout
  u16* query = slotB;      // alias chain: query -> tmp
  u16* headsout = slotA;
  u16* tmpb = slotB;

  detect_mask_kernel<<<1, 256, 0, stream>>>((const u32*)mask, flag);
  maskprep_kernel<<<8192, 256, 0, stream>>>(mask, flag, maskb);
  transpose_cvt_kernel<<<512, 256, 0, stream>>>(Wstep, 512, 0, 515, 576, WstepT);
  slice_cvt_kernel<<<1024, 256, 0, stream>>>(Wkvl, W2bf);
  cvt_bf_kernel<<<1024, 256, 0, stream>>>(Wout, Woutbf);
  // WfT[d][h] = sum_o W2[d][o] * Wout[h][o]
  gemm128_plain_kernel<<<16, 256, 0, stream>>>(W2bf, Woutbf, WfT);
  cvt_pmean_kernel<<<1024, 256, 0, stream>>>(emb, ebf, pmean);
  fixedctx_kernel<<<256, 256, 0, stream>>>(pmean, Wc, fixedc);
  build_nextn_kernel<<<8192, 256, 0, stream>>>(ebf, cur, ucap, ubat, ctim, nextn);

  // KV projection: ebf [131072 x 512] x WkT-on-the-fly -> Kbuf/Vtbuf
  {
    // WkT must be ready: K/V part of W_kvlogit, transposed. Reuse transpose_cvt
    // into a fresh region before gemm256 (kept out of the alias chains).
  }
  // K/V weight transpose (cols 0..1023 of W_kvlogit)
  static_assert(true, "");
  {
    u16* WkT = (u16*)take((size_t)1024 * 512 * 2);
    transpose_cvt_kernel<<<1024, 256, 0, stream>>>(Wkvl, 1536, 0, 512, 512, WkT);
    gemm256_kv_kernel<<<2048, 512, 0, stream>>>(ebf, WkT, Kbuf, Vtbuf);
  }
  // query = fixed_context + nextn @ WstepT   (K = 576, grid 128 mtiles x 4 = 512)
  gemmW_kernel<0><<<512, 512, 0, stream>>>(nextn, WstepT, 576, 576, 576, query, fixedc);
  // attention
  attn_kernel<<<8192, 256, 0, stream>>>(query, Kbuf, Vtbuf, (const u64*)maskb, headsout);
  // tmp = headsout @ WfT  (fused Wout*W2)
  gemmW_kernel<1><<<512, 512, 0, stream>>>(headsout, WfT, 512, 512, 512, tmpb, nullptr);
  // logits (transposed-batched): per b, C[n][t] = sum_d ebf_b[n][d]*tmp_b[t][d]
  gemmW_kernel<2><<<512, 512, 0, stream>>>(ebf, tmpb, 512, 512, 512, d_out, maskb);
  // in-place log-softmax
  logsoftmax_kernel<<<8192, 256, 0, stream>>>((float*)d_out);
}

// Round 5
// 655.112 us; speedup vs baseline: 1.6448x; 1.0614x over previous
//
#include <hip/hip_runtime.h>
#include <hip/hip_bf16.h>
#include <stdint.h>

typedef unsigned short u16;
typedef unsigned int   u32;
typedef unsigned long long u64;
typedef __attribute__((ext_vector_type(4))) float f32x4;
typedef __attribute__((ext_vector_type(8))) short s16x8;

#define NEG_INF (-1e9f)

__device__ __forceinline__ u16 f2bf(float f) {
  __hip_bfloat16 h = __float2bfloat16(f);
  return __builtin_bit_cast(u16, h);
}

__device__ __forceinline__ f32x4 mfma16(s16x8 a, s16x8 b, f32x4 c) {
  return __builtin_amdgcn_mfma_f32_16x16x32_bf16(a, b, c, 0, 0, 0);
}

// async global->LDS, 16 B per lane; LDS dest is wave-uniform base + lane*16
#define GLOAD16(g, l)                                                        \
  __builtin_amdgcn_global_load_lds(                                          \
      (const __attribute__((address_space(1))) unsigned int*)(g),            \
      (__attribute__((address_space(3))) unsigned int*)(l), 16, 0, 0)

#define WAITV(n) asm volatile("s_waitcnt vmcnt(" #n ")" ::: "memory")
#define WAITLGKM asm volatile("s_waitcnt lgkmcnt(0)" ::: "memory")
#define SBAR __builtin_amdgcn_sched_barrier(0)
#define HBAR __builtin_amdgcn_s_barrier()

// ---------------------------------------------------------------- mask prep
__global__ void detect_mask_kernel(const u32* __restrict__ mraw, u32* __restrict__ flag) {
  __shared__ int any;
  if (threadIdx.x == 0) any = 0;
  __syncthreads();
  int loc = 0;
  for (int i = threadIdx.x; i < 16384; i += 256) {
    u32 v = mraw[i];
    if (v & 0xFFFFFF00u) loc = 1;  // int32 0/1 values never set high bytes
  }
  if (loc) atomicOr(&any, 1);
  __syncthreads();
  if (threadIdx.x == 0) *flag = any ? 1u : 4u;
}

__global__ __launch_bounds__(256) void maskprep_kernel(const void* __restrict__ mraw,
                                                       const u32* __restrict__ flag,
                                                       unsigned char* __restrict__ mb) {
  long long idx = (long long)blockIdx.x * 256 + threadIdx.x;  // B*T*64 = 2097152
  long long bt = idx >> 6;
  int ch = (int)(idx & 63);
  unsigned char byte = 0;
  if (*flag == 1) {
    u64 v = *(const u64*)((const unsigned char*)mraw + bt * 512 + ch * 8);
#pragma unroll
    for (int i = 0; i < 8; i++)
      if ((v >> (8 * i)) & 0xFFull) byte |= (unsigned char)(1 << i);
  } else {
    const int* p = (const int*)mraw + bt * 512 + ch * 8;
#pragma unroll
    for (int i = 0; i < 8; i++)
      if (p[i]) byte |= (unsigned char)(1 << i);
  }
  mb[idx] = byte;
}

// ---------------------------------------------------------------- weight prep
__global__ void transpose_cvt_kernel(const float* __restrict__ in, int ld_in, int off,
                                     int kreal, int CO, u16* __restrict__ outp) {
  int i = blockIdx.x;
  for (int j = threadIdx.x; j < CO; j += 256) {
    float v = (j < kreal) ? in[(long long)j * ld_in + off + i] : 0.0f;
    outp[(long long)i * CO + j] = f2bf(v);
  }
}

__global__ void slice_cvt_kernel(const float* __restrict__ in, u16* __restrict__ outp) {
  long long idx = (long long)blockIdx.x * 256 + threadIdx.x;  // 262144
  long long dd = idx >> 9;
  int hh = (int)(idx & 511);
  outp[idx] = f2bf(in[dd * 1536 + 1024 + hh]);
}

__global__ void cvt_bf_kernel(const float* __restrict__ in, u16* __restrict__ outp) {
  long long idx = (long long)blockIdx.x * 256 + threadIdx.x;
  outp[idx] = f2bf(in[idx]);
}

// ------------------------------------------- emb fp32 -> bf16 + partial mean (fused)
__global__ __launch_bounds__(256) void cvt_pmean_kernel(const float* __restrict__ emb,
                                                        u16* __restrict__ ebf,
                                                        float* __restrict__ pmean) {
  const int bq = blockIdx.x >> 2, nq = blockIdx.x & 3;
  const int tid = threadIdx.x;
  const int ro = tid >> 7;
  const int c4 = (tid & 127) << 2;
  const long long base = ((long long)bq * 512 + nq * 128) * 512;
  float s[4] = {0.f, 0.f, 0.f, 0.f};
  for (int n = ro; n < 128; n += 2) {
    f32x4 v = *(const f32x4*)&emb[base + (long long)n * 512 + c4];
    u16 pk[4];
#pragma unroll
    for (int i = 0; i < 4; i++) { s[i] += v[i]; pk[i] = f2bf(v[i]); }
    *(u64*)&ebf[base + (long long)n * 512 + c4] =
        (u64)pk[0] | ((u64)pk[1] << 16) | ((u64)pk[2] << 32) | ((u64)pk[3] << 48);
  }
  __shared__ float ls[2][512];
#pragma unroll
  for (int i = 0; i < 4; i++) ls[ro][c4 + i] = s[i];
  __syncthreads();
  float* dst = pmean + (long long)blockIdx.x * 512;
  dst[tid] = ls[0][tid] + ls[1][tid];
  dst[tid + 256] = ls[0][tid + 256] + ls[1][tid + 256];
}

__global__ __launch_bounds__(256) void fixedctx_kernel(const float* __restrict__ pmean,
                                                       const float* __restrict__ Wc,
                                                       float* __restrict__ fixedc) {
  __shared__ float mf[512];
  int b = blockIdx.x;
  const float* p = pmean + (long long)b * 4 * 512;
  for (int d = threadIdx.x; d < 512; d += 256)
    mf[d] = (p[d] + p[512 + d] + p[1024 + d] + p[1536 + d]) * (1.0f / 512.0f);
  __syncthreads();
  for (int h = threadIdx.x; h < 512; h += 256) {
    float s = 0.f;
    for (int d = 0; d < 512; ++d) s += mf[d] * Wc[(long long)d * 512 + h];
    fixedc[(long long)b * 512 + h] = s;
  }
}

// ---------------------------------------------------------------- next-node features
__global__ __launch_bounds__(256) void build_nextn_kernel(
    const u16* __restrict__ ebf, const int* __restrict__ cur,
    const float* __restrict__ ucap, const float* __restrict__ ubat,
    const float* __restrict__ ctim, u16* __restrict__ outp) {
  const long long rowm = (long long)blockIdx.x * 4 + (threadIdx.x >> 6);
  const int lane = threadIdx.x & 63;
  const int b = (int)(rowm >> 7);
  const int node = cur[rowm];
  const u16* src = ebf + ((long long)b * 512 + node) * 512;
  u16* dst = outp + rowm * 576;
  *(s16x8*)&dst[lane * 8] = *(const s16x8*)&src[lane * 8];
  {
    const int c = 512 + lane;
    float v = (lane == 0) ? 1.0f - ucap[rowm]
            : (lane == 1) ? 1.0f - ubat[rowm]
            : (lane == 2) ? ctim[rowm] : 0.0f;
    dst[c] = f2bf(v);
  }
}

// =============================================================================
// Persistent KV GEMM: grid 256 (1 block/CU), each block: fixed ntile, walks 8
// m-tiles = 64 continuous K-tile iters. 256x256 tile, BK=64, 8 waves (2Mx4N).
// 2 barriers/tile: entry(vmcnt) + post-reads; both stages issued after barrier2.
// Ping-pong A-frag prefetch hides ds_read latency under MFMAs.
// =============================================================================
__global__ __launch_bounds__(512, 1) void gemm256_kv_kernel(
    const u16* __restrict__ A, const u16* __restrict__ Bw,
    u16* __restrict__ Kbuf, u16* __restrict__ Vtbuf) {
  __shared__ __align__(16) char lds[131072];
  const int tid = threadIdx.x;
  const int lane = tid & 63;
  const int wid = tid >> 6;
  const int wr = wid >> 2, wc = wid & 3;

  // XCD x gets mtiles [x*64, x*64+64); block i-in-XCD: ntile = i&3, mslot = i>>2
  const int p = blockIdx.x;           // 0..255
  const int x = p & 7;
  const int i = p >> 3;               // 0..31
  const int ntile = i & 3;
  const int mslot = i >> 2;           // 0..7
  const long long mbase = ((long long)x * 64 + mslot * 8) * 256;
  const long long nrow0 = (long long)ntile * 256;

  const int rsub = tid >> 3;
  const int ssl = tid & 7;

#define MROW(tt2) (mbase + (long long)(((tt2) >> 3)) * 256)
#define KOF(tt2) (((tt2) & 7) * 64)

#define STAGEB4(dd, tt2)                                                      \
  {                                                                           \
    _Pragma("unroll") for (int hg = 0; hg < 4; hg++) {                        \
      const int half_ = hg >> 1, g_ = hg & 1;                                 \
      const int r_ = half_ * 128 + g_ * 64 + rsub;                            \
      const int colel_ = KOF(tt2) + ((ssl ^ (r_ & 7)) << 3);                  \
      GLOAD16(Bw + (nrow0 + r_) * 512ll + colel_,                             \
              lds + (dd) * 65536 + 32768 + half_ * 16384 + g_ * 8192 + wid * 1024); \
    }                                                                         \
  }
#define STAGEA4(dd, tt2)                                                      \
  {                                                                           \
    _Pragma("unroll") for (int hg = 0; hg < 4; hg++) {                        \
      const int half_ = hg >> 1, g_ = hg & 1;                                 \
      const int r_ = half_ * 128 + g_ * 64 + rsub;                            \
      const int colel_ = KOF(tt2) + ((ssl ^ (r_ & 7)) << 3);                  \
      GLOAD16(A + (MROW(tt2) + r_) * 512ll + colel_,                          \
              lds + (dd) * 65536 + half_ * 16384 + g_ * 8192 + wid * 1024);   \
    }                                                                         \
  }

#define READ_A(dst, ph)                                                       \
  _Pragma("unroll") for (int mi = 0; mi < 2; mi++)                            \
  _Pragma("unroll") for (int ks = 0; ks < 2; ks++) {                          \
    const int arow = ((ph) * 2 + mi) * 16 + fr;                               \
    dst[mi][ks] = *(const s16x8*)(ab + arow * 128 + ((ks * 64 + fq * 16) ^ swz)); \
  }
#define MFMA_PH(src, ph)                                                      \
  _Pragma("unroll") for (int mi = 0; mi < 2; mi++)                            \
  _Pragma("unroll") for (int nb = 0; nb < 4; nb++)                            \
  _Pragma("unroll") for (int ks = 0; ks < 2; ks++)                            \
    acc[(ph) * 2 + mi][nb] = mfma16(src[mi][ks], bfrag[nb][ks], acc[(ph) * 2 + mi][nb]);

  const int fr = lane & 15;
  const int fq = lane >> 4;
  const int swz = (lane & 7) << 4;

  // prologue: tiles 0 and 1
  STAGEB4(0, 0); STAGEA4(0, 0);
  STAGEB4(1, 1); STAGEA4(1, 1);

  f32x4 acc[8][4];

#pragma unroll 1
  for (int j = 0; j < 8; j++) {
#pragma unroll
    for (int ii = 0; ii < 8; ii++)
#pragma unroll
      for (int jj = 0; jj < 4; jj++) acc[ii][jj] = (f32x4){0.f, 0.f, 0.f, 0.f};

#pragma unroll 1
    for (int t8 = 0; t8 < 8; t8++) {
      const int tt = j * 8 + t8;
      const int d = tt & 1;
      if (tt == 63) { WAITV(0); } else { WAITV(8); }
      HBAR; SBAR;

      const char* ab = lds + d * 65536 + wr * 16384;
      const char* bb = lds + d * 65536 + 32768 + (wc >> 1) * 16384;

      s16x8 bfrag[4][2];
#pragma unroll
      for (int nb = 0; nb < 4; nb++)
#pragma unroll
        for (int ks = 0; ks < 2; ks++) {
          const int brow = (wc & 1) * 64 + nb * 16 + fr;
          bfrag[nb][ks] =
              *(const s16x8*)(bb + brow * 128 + ((ks * 64 + fq * 16) ^ swz));
        }
      s16x8 afA[2][2], afB[2][2];
      READ_A(afA, 0);
      WAITLGKM; SBAR;
      READ_A(afB, 1);
      __builtin_amdgcn_s_setprio(1);
      MFMA_PH(afA, 0);
      __builtin_amdgcn_s_setprio(0);
      WAITLGKM; SBAR;
      READ_A(afA, 2);
      __builtin_amdgcn_s_setprio(1);
      MFMA_PH(afB, 1);
      __builtin_amdgcn_s_setprio(0);
      WAITLGKM; SBAR;
      READ_A(afB, 3);
      __builtin_amdgcn_s_setprio(1);
      MFMA_PH(afA, 2);
      __builtin_amdgcn_s_setprio(0);
      WAITLGKM; SBAR;
      HBAR;  // all waves' reads of buffer d complete
      if (tt + 2 < 64) { STAGEB4(d, tt + 2); STAGEA4(d, tt + 2); }
      __builtin_amdgcn_s_setprio(1);
      MFMA_PH(afB, 3);
      __builtin_amdgcn_s_setprio(0);
    }

    // epilogue for m-tile j
    const long long mrow0 = mbase + (long long)j * 256;
    const int colbase = (int)(ntile * 256) + wc * 64;
#pragma unroll
    for (int mb = 0; mb < 8; mb++) {
      const long long row = mrow0 + wr * 128 + mb * 16 + fq * 4;
      const int bbx = (int)(row >> 9);
      const int node0 = (int)(row & 511);
#pragma unroll
      for (int nb = 0; nb < 4; nb++) {
        const int col = colbase + nb * 16 + fr;
        const int hh = (col >> 6) & 7;
        const int kk = col & 63;
        if (col < 512) {  // K part: [b,h,node,kk]
          u16* dst = Kbuf + (((long long)(bbx * 8 + hh) * 512 + node0) << 6) + kk;
#pragma unroll
          for (int q = 0; q < 4; q++) dst[(long long)q << 6] = f2bf(acc[mb][nb][q]);
        } else {          // V part: [b,h,kk,node]
          u16 pk[4];
#pragma unroll
          for (int q = 0; q < 4; q++) pk[q] = f2bf(acc[mb][nb][q]);
          *(u64*)(Vtbuf + (((long long)(bbx * 8 + hh) * 64 + kk) << 9) + node0) =
              (u64)pk[0] | ((u64)pk[1] << 16) | ((u64)pk[2] << 32) | ((u64)pk[3] << 48);
        }
      }
    }
  }
#undef STAGEB4
#undef STAGEA4
#undef READ_A
#undef MFMA_PH
#undef MROW
#undef KOF
}

// =============================================================================
// gemmW: BM=256, BN=128, BK=64, 8 waves (4M x 2N), 2-barrier schedule.
// MODE 0: query epilogue (+fixedc), MODE 1: plain bf16 out. N = 512 fixed.
// LDS: A 2x32KB @0, B 2x16KB @65536.
// =============================================================================
template <int MODE>
__global__ __launch_bounds__(512, 1) void gemmW_kernel(
    const u16* __restrict__ A, const u16* __restrict__ Bv,
    int ldA, int ldB, int NT,
    void* __restrict__ out0, const void* __restrict__ aux) {
  __shared__ __align__(16) char lds[98304];
  const int tid = threadIdx.x;
  const int lane = tid & 63;
  const int wid = tid >> 6;
  const int wr = wid >> 1, wc = wid & 1;

  const int p = blockIdx.x;
  const int chunk = (int)(gridDim.x >> 3);
  const int wk = (p & 7) * chunk + (p >> 3);
  const int mtile = wk >> 2;
  const int ntile = wk & 3;
  const long long mrow0 = (long long)mtile * 256;
  const u16* Bb = Bv + (long long)ntile * 128 * ldB;

  const int rsub = tid >> 3;
  const int ssl = tid & 7;

#define STAGEA(dd, k0)                                                        \
  {                                                                           \
    _Pragma("unroll") for (int g_ = 0; g_ < 4; g_++) {                        \
      const int r_ = g_ * 64 + rsub;                                          \
      const int colel_ = (k0) + ((ssl ^ (r_ & 7)) << 3);                      \
      GLOAD16(A + (mrow0 + r_) * (long long)ldA + colel_,                     \
              lds + (dd) * 32768 + g_ * 8192 + wid * 1024);                   \
    }                                                                         \
  }
#define STAGEB(dd, k0)                                                        \
  {                                                                           \
    _Pragma("unroll") for (int g_ = 0; g_ < 2; g_++) {                        \
      const int r_ = g_ * 64 + rsub;                                          \
      const int colel_ = (k0) + ((ssl ^ (r_ & 7)) << 3);                      \
      GLOAD16(Bb + r_ * (long long)ldB + colel_,                              \
              lds + 65536 + (dd) * 16384 + g_ * 8192 + wid * 1024);           \
    }                                                                         \
  }
#define READ_A1(dst, ph)                                                      \
  _Pragma("unroll") for (int ks = 0; ks < 2; ks++) {                          \
    const int arow = (ph) * 16 + fr;                                          \
    dst[ks] = *(const s16x8*)(ab + arow * 128 + ((ks * 64 + fq * 16) ^ swz)); \
  }
#define MFMA_P(src, ph)                                                       \
  _Pragma("unroll") for (int nb = 0; nb < 4; nb++)                            \
  _Pragma("unroll") for (int ks = 0; ks < 2; ks++)                            \
    acc[ph][nb] = mfma16(src[ks], bfrag[nb][ks], acc[ph][nb]);

  f32x4 acc[4][4];
#pragma unroll
  for (int ii = 0; ii < 4; ii++)
#pragma unroll
    for (int jj = 0; jj < 4; jj++) acc[ii][jj] = (f32x4){0.f, 0.f, 0.f, 0.f};

  STAGEB(0, 0); STAGEA(0, 0);
  STAGEB(1, 64); STAGEA(1, 64);

  const int fr = lane & 15;
  const int fq = lane >> 4;
  const int swz = (lane & 7) << 4;

#pragma unroll 1
  for (int t = 0; t < NT; t++) {
    const int d = t & 1;
    if (t == NT - 1) { WAITV(0); } else { WAITV(6); }
    HBAR; SBAR;

    const char* ab = lds + d * 32768 + wr * 8192;
    const char* bb = lds + 65536 + d * 16384 + wc * 8192;

    s16x8 bfrag[4][2];
#pragma unroll
    for (int nb = 0; nb < 4; nb++)
#pragma unroll
      for (int ks = 0; ks < 2; ks++) {
        const int brow = nb * 16 + fr;
        bfrag[nb][ks] =
            *(const s16x8*)(bb + brow * 128 + ((ks * 64 + fq * 16) ^ swz));
      }
    s16x8 afA[2], afB[2];
    READ_A1(afA, 0);
    WAITLGKM; SBAR;
    READ_A1(afB, 1);
    __builtin_amdgcn_s_setprio(1);
    MFMA_P(afA, 0);
    __builtin_amdgcn_s_setprio(0);
    WAITLGKM; SBAR;
    READ_A1(afA, 2);
    __builtin_amdgcn_s_setprio(1);
    MFMA_P(afB, 1);
    __builtin_amdgcn_s_setprio(0);
    WAITLGKM; SBAR;
    READ_A1(afB, 3);
    __builtin_amdgcn_s_setprio(1);
    MFMA_P(afA, 2);
    __builtin_amdgcn_s_setprio(0);
    WAITLGKM; SBAR;
    HBAR;
    if (t + 2 < NT) { STAGEB(d, (t + 2) * 64); STAGEA(d, (t + 2) * 64); }
    __builtin_amdgcn_s_setprio(1);
    MFMA_P(afB, 3);
    __builtin_amdgcn_s_setprio(0);
  }
#undef STAGEA
#undef STAGEB
#undef READ_A1
#undef MFMA_P

  const int colbase = ntile * 128 + wc * 64;
#pragma unroll
  for (int mb = 0; mb < 4; mb++) {
    const long long row0 = mrow0 + wr * 64 + mb * 16 + fq * 4;
#pragma unroll
    for (int nb = 0; nb < 4; nb++) {
      const int col = colbase + nb * 16 + fr;
#pragma unroll
      for (int q = 0; q < 4; q++) {
        const long long row = row0 + q;
        float v = acc[mb][nb][q];
        if (MODE == 0) {
          const float* fc = (const float*)aux;
          v += fc[(row >> 7) * 512 + col];
        }
        ((u16*)out0)[row * 512 + col] = f2bf(v);
      }
    }
  }
}

// =============================================================================
// gemm_lsm: logits GEMM fused with tanh/mask + log-softmax.
// Per block: one (b, t-half): C[node 0..511][t 0..63] = ebf_b . tmp_b^T.
// BM=512 (8 waves x 64 rows), BN=64, BK=64, NT=8. LDS: A 2x64KB, B 2x8KB.
// Epilogue: full node-dim present -> cross-wave LSM reduce, store f32 out.
// =============================================================================
__global__ __launch_bounds__(512, 1) void gemm_lsm_kernel(
    const u16* __restrict__ ebf, const u16* __restrict__ tmpb,
    const u64* __restrict__ maskb, float* __restrict__ outp) {
  __shared__ __align__(16) char lds[147456];
  const int tid = threadIdx.x;
  const int lane = tid & 63;
  const int wid = tid >> 6;

  const int p = blockIdx.x;           // 512 blocks
  const int x = p & 7;
  const int i = p >> 3;               // 0..63
  const int thalf = i & 1;
  const int b = x * 32 + (i >> 1);

  const u16* Ab = ebf + (long long)b * 262144;
  const u16* Bb = tmpb + (long long)b * 65536 + (long long)thalf * 64 * 512;

  const int rsub = tid >> 3;
  const int ssl = tid & 7;

#define STAGEA(dd, k0)                                                        \
  {                                                                           \
    _Pragma("unroll") for (int g_ = 0; g_ < 8; g_++) {                        \
      const int r_ = g_ * 64 + rsub;                                          \
      const int colel_ = (k0) + ((ssl ^ (r_ & 7)) << 3);                      \
      GLOAD16(Ab + r_ * 512ll + colel_,                                       \
              lds + (dd) * 65536 + g_ * 8192 + wid * 1024);                   \
    }                                                                         \
  }
#define STAGEB(dd, k0)                                                        \
  {                                                                           \
    const int r_ = rsub;                                                      \
    const int colel_ = (k0) + ((ssl ^ (r_ & 7)) << 3);                        \
    GLOAD16(Bb + r_ * 512ll + colel_, lds + 131072 + (dd) * 8192 + wid * 1024); \
  }
#define READ_A1(dst, ph)                                                      \
  _Pragma("unroll") for (int ks = 0; ks < 2; ks++) {                          \
    const int arow = (ph) * 16 + fr;                                          \
    dst[ks] = *(const s16x8*)(ab + arow * 128 + ((ks * 64 + fq * 16) ^ swz)); \
  }
#define MFMA_P(src, ph)                                                       \
  _Pragma("unroll") for (int nb = 0; nb < 4; nb++)                            \
  _Pragma("unroll") for (int ks = 0; ks < 2; ks++)                            \
    acc[ph][nb] = mfma16(src[ks], bfrag[nb][ks], acc[ph][nb]);

  f32x4 acc[4][4];
#pragma unroll
  for (int ii = 0; ii < 4; ii++)
#pragma unroll
    for (int jj = 0; jj < 4; jj++) acc[ii][jj] = (f32x4){0.f, 0.f, 0.f, 0.f};

  STAGEB(0, 0); STAGEA(0, 0);
  STAGEB(1, 64); STAGEA(1, 64);

  const int fr = lane & 15;
  const int fq = lane >> 4;
  const int swz = (lane & 7) << 4;

#pragma unroll 1
  for (int t = 0; t < 8; t++) {
    const int d = t & 1;
    if (t == 7) { WAITV(0); } else { WAITV(9); }
    HBAR; SBAR;

    const char* ab = lds + d * 65536 + wid * 8192;
    const char* bb = lds + 131072 + d * 8192;

    s16x8 bfrag[4][2];
#pragma unroll
    for (int nb = 0; nb < 4; nb++)
#pragma unroll
      for (int ks = 0; ks < 2; ks++) {
        const int brow = nb * 16 + fr;
        bfrag[nb][ks] =
            *(const s16x8*)(bb + brow * 128 + ((ks * 64 + fq * 16) ^ swz));
      }
    s16x8 afA[2], afB[2];
    READ_A1(afA, 0);
    WAITLGKM; SBAR;
    READ_A1(afB, 1);
    __builtin_amdgcn_s_setprio(1);
    MFMA_P(afA, 0);
    __builtin_amdgcn_s_setprio(0);
    WAITLGKM; SBAR;
    READ_A1(afA, 2);
    __builtin_amdgcn_s_setprio(1);
    MFMA_P(afB, 1);
    __builtin_amdgcn_s_setprio(0);
    WAITLGKM; SBAR;
    READ_A1(afB, 3);
    __builtin_amdgcn_s_setprio(1);
    MFMA_P(afA, 2);
    __builtin_amdgcn_s_setprio(0);
    WAITLGKM; SBAR;
    HBAR;
    if (t + 2 < 8) { STAGEB(d, (t + 2) * 64); STAGEA(d, (t + 2) * 64); }
    __builtin_amdgcn_s_setprio(1);
    MFMA_P(afB, 3);
    __builtin_amdgcn_s_setprio(0);
  }
#undef STAGEA
#undef STAGEB
#undef READ_A1
#undef MFMA_P

  // ---- fused tanh/mask + log-softmax epilogue ----
  // last tile used buffer d=1 -> reduce arrays live in buffer-0 A region.
  float* red = (float*)lds;  // mlds[8][64] @0, mfin[64] @512, slds[8][64] @576, lsef[64] @1088
  const float rs512 = 0.044194173824159216f;  // 1/sqrt(512)
  const float L2E = 1.4426950408889634f;

  float lmax[4];
#pragma unroll
  for (int nb = 0; nb < 4; nb++) {
    const int tl = nb * 16 + fr;
    const long long orow = (long long)b * 128 + thalf * 64 + tl;
    const u64 w = maskb[orow * 8 + wid];
    float mx = -3.0e38f;
#pragma unroll
    for (int mb = 0; mb < 4; mb++) {
      f32x4 r;
#pragma unroll
      for (int q = 0; q < 4; q++) {
        float xv = acc[mb][nb][q] * rs512;
        float e = exp2f(xv * 2.8853900817779268f);  // e^{2x}
        float th = 1.0f - 2.0f * __builtin_amdgcn_rcpf(e + 1.0f);
        float lg = 10.0f * th;
        const int bitn = mb * 16 + fq * 4 + q;
        if ((w >> bitn) & 1ull) lg = NEG_INF;
        r[q] = lg;
        mx = fmaxf(mx, lg);
      }
      acc[mb][nb] = r;
    }
    mx = fmaxf(mx, __shfl_xor(mx, 16));
    mx = fmaxf(mx, __shfl_xor(mx, 32));
    lmax[nb] = mx;
  }
  __syncthreads();  // also ensures all LDS reads of the K-loop are done
  if (lane < 16) {
#pragma unroll
    for (int nb = 0; nb < 4; nb++) red[wid * 64 + nb * 16 + lane] = lmax[nb];
  }
  __syncthreads();
  if (tid < 64) {
    float m = red[tid];
#pragma unroll
    for (int ww = 1; ww < 8; ww++) m = fmaxf(m, red[ww * 64 + tid]);
    red[512 + tid] = m;
  }
  __syncthreads();
  float lsum[4];
#pragma unroll
  for (int nb = 0; nb < 4; nb++) {
    const float m = red[512 + nb * 16 + fr];
    float s = 0.f;
#pragma unroll
    for (int mb = 0; mb < 4; mb++)
#pragma unroll
      for (int q = 0; q < 4; q++) s += exp2f((acc[mb][nb][q] - m) * L2E);
    s += __shfl_xor(s, 16);
    s += __shfl_xor(s, 32);
    lsum[nb] = s;
  }
  if (lane < 16) {
#pragma unroll
    for (int nb = 0; nb < 4; nb++) red[576 + wid * 64 + nb * 16 + lane] = lsum[nb];
  }
  __syncthreads();
  if (tid < 64) {
    float s = red[576 + tid];
#pragma unroll
    for (int ww = 1; ww < 8; ww++) s += red[576 + ww * 64 + tid];
    red[1088 + tid] = red[512 + tid] + logf(s);
  }
  __syncthreads();
#pragma unroll
  for (int nb = 0; nb < 4; nb++) {
    const int tl = nb * 16 + fr;
    const long long orow = (long long)b * 128 + thalf * 64 + tl;
    const float lse = red[1088 + tl];
#pragma unroll
    for (int mb = 0; mb < 4; mb++) {
      const int node0 = wid * 64 + mb * 16 + fq * 4;
      f32x4 r = acc[mb][nb];
#pragma unroll
      for (int q = 0; q < 4; q++) r[q] -= lse;
      *(f32x4*)&outp[orow * 512 + node0] = r;
    }
  }
}

// ---------------- small 128^2 GEMM (used once for WfT)
__global__ __launch_bounds__(256) void gemm128_plain_kernel(
    const u16* __restrict__ A, const u16* __restrict__ Bv, u16* __restrict__ outp) {
  __shared__ u16 lA[128 * 32];
  __shared__ u16 lB[128 * 32];
  const int tid = threadIdx.x;
  const int lane = tid & 63;
  const int wave = tid >> 6;
  const int wr = wave >> 1, wc = wave & 1;

  const int p = blockIdx.x;  // grid 16
  const int wk = (p & 7) * 2 + (p >> 3);
  const int ntile = wk & 3;
  const int mtile = wk >> 2;
  const long long arow0 = (long long)mtile * 128;
  const long long brow0 = (long long)ntile * 128;

  f32x4 acc[4][4];
#pragma unroll
  for (int i = 0; i < 4; i++)
#pragma unroll
    for (int j = 0; j < 4; j++) acc[i][j] = (f32x4){0.f, 0.f, 0.f, 0.f};

  const int sc8 = (lane & 3) << 3;

  for (int k0 = 0; k0 < 512; k0 += 32) {
    __syncthreads();
#pragma unroll
    for (int i = 0; i < 2; i++) {
      GLOAD16(A + (arow0 + i * 64 + wave * 16 + (lane >> 2)) * 512ll + k0 + sc8,
              &lA[(i * 64 + wave * 16) * 32]);
      GLOAD16(Bv + (brow0 + i * 64 + wave * 16 + (lane >> 2)) * 512ll + k0 + sc8,
              &lB[(i * 64 + wave * 16) * 32]);
    }
    __syncthreads();
    s16x8 af[4], bfr[4];
#pragma unroll
    for (int i = 0; i < 4; i++)
      af[i] = *(const s16x8*)&lA[(wr * 64 + i * 16 + (lane & 15)) * 32 + ((lane >> 4) << 3)];
#pragma unroll
    for (int j = 0; j < 4; j++)
      bfr[j] = *(const s16x8*)&lB[(wc * 64 + j * 16 + (lane & 15)) * 32 + ((lane >> 4) << 3)];
#pragma unroll
    for (int i = 0; i < 4; i++)
#pragma unroll
      for (int j = 0; j < 4; j++) acc[i][j] = mfma16(af[i], bfr[j], acc[i][j]);
  }

#pragma unroll
  for (int i = 0; i < 4; i++) {
    const int rl = wr * 64 + i * 16 + ((lane >> 4) << 2);
#pragma unroll
    for (int j = 0; j < 4; j++) {
      const int cl = wc * 64 + j * 16 + (lane & 15);
#pragma unroll
      for (int q = 0; q < 4; q++)
        outp[(arow0 + rl + q) * 512 + brow0 + cl] = f2bf(acc[i][j][q]);
    }
  }
}

// ---------------------------------------------------------------- fused attention
__global__ __launch_bounds__(256) void attn_kernel(
    const u16* __restrict__ query, const u16* __restrict__ Kbuf,
    const u16* __restrict__ Vtbuf, const u64* __restrict__ maskbits,
    u16* __restrict__ headsout) {
  const int p = blockIdx.x;
  const int fb = (p & 7) * 1024 + (p >> 3);
  const int tt = fb & 3;
  const int h = (fb >> 2) & 7;
  const int b = fb >> 5;
  const int tid = threadIdx.x;
  const int lane = tid & 63;
  const int wave = tid >> 6;

  __shared__ u16 P[32 * 512];
  __shared__ u64 mrows[32 * 8];
  __shared__ float rsw[4][32];
  __shared__ float rst[32];

  {
    int t = tid >> 3, w = tid & 7;
    mrows[tid] = maskbits[(((long long)b * 128) + tt * 32 + t) * 8 + w];
  }

  const u16* Qb = query + ((long long)(b * 128 + tt * 32)) * 512 + h * 64;
  s16x8 qf[2][2];
#pragma unroll
  for (int tf = 0; tf < 2; tf++)
#pragma unroll
    for (int ks = 0; ks < 2; ks++)
      qf[tf][ks] = *(const s16x8*)(Qb + (long long)(tf * 16 + (lane & 15)) * 512 +
                                   ks * 32 + ((lane >> 4) << 3));

  const int ns = wave * 128;
  const u16* Kb = Kbuf + ((long long)(b * 8 + h) * 512) * 64;
  f32x4 s[8][2];
#pragma unroll
  for (int nf = 0; nf < 8; nf++)
#pragma unroll
    for (int tf = 0; tf < 2; tf++) s[nf][tf] = (f32x4){0.f, 0.f, 0.f, 0.f};
#pragma unroll
  for (int nf = 0; nf < 8; nf++) {
#pragma unroll
    for (int ks = 0; ks < 2; ks++) {
      s16x8 kf = *(const s16x8*)(Kb + (long long)(ns + nf * 16 + (lane & 15)) * 64 +
                                 ks * 32 + ((lane >> 4) << 3));
#pragma unroll
      for (int tf = 0; tf < 2; tf++) s[nf][tf] = mfma16(kf, qf[tf][ks], s[nf][tf]);
    }
  }
  __syncthreads();

  const float CE = 0.18033688011112043f;  // (1/8) * log2(e)
  const int tcol = lane & 15;
  float psum[2] = {0.f, 0.f};
#pragma unroll
  for (int nf = 0; nf < 8; nf++) {
#pragma unroll
    for (int tf = 0; tf < 2; tf++) {
      const int trow = tf * 16 + tcol;
      const u64 w0 = mrows[trow * 8 + wave * 2];
      const u64 w1 = mrows[trow * 8 + wave * 2 + 1];
      u16 pk[4];
#pragma unroll
      for (int q = 0; q < 4; q++) {
        const int nl = nf * 16 + ((lane >> 4) << 2) + q;
        const u64 w = (nl & 64) ? w1 : w0;
        float pv = exp2f(s[nf][tf][q] * CE);
        if ((w >> (nl & 63)) & 1ull) pv = 0.0f;
        psum[tf] += pv;
        pk[q] = f2bf(pv);
      }
      const int nb = (ns + nf * 16 + ((lane >> 4) << 2)) * 2;
      const int off = trow * 1024 + (nb ^ ((trow & 7) << 4));
      u64 pd = (u64)pk[0] | ((u64)pk[1] << 16) | ((u64)pk[2] << 32) | ((u64)pk[3] << 48);
      *(u64*)((char*)P + off) = pd;
    }
  }
#pragma unroll
  for (int tf = 0; tf < 2; tf++) {
    float v = psum[tf];
    v += __shfl_xor(v, 16);
    v += __shfl_xor(v, 32);
    if ((lane >> 4) == 0) rsw[wave][tf * 16 + tcol] = v;
  }
  __syncthreads();
  if (tid < 32) rst[tid] = rsw[0][tid] + rsw[1][tid] + rsw[2][tid] + rsw[3][tid];
  __syncthreads();

  const u16* Vb = Vtbuf + ((long long)(b * 8 + h) * 64 + wave * 16) * 512;
  f32x4 o[2];
  o[0] = (f32x4){0.f, 0.f, 0.f, 0.f};
  o[1] = (f32x4){0.f, 0.f, 0.f, 0.f};
#pragma unroll
  for (int ksn = 0; ksn < 16; ksn++) {
    s16x8 vf = *(const s16x8*)(Vb + (long long)(lane & 15) * 512 + ksn * 32 + ((lane >> 4) << 3));
#pragma unroll
    for (int mf = 0; mf < 2; mf++) {
      const int trow = mf * 16 + (lane & 15);
      const int nb = (ksn * 32 + ((lane >> 4) << 3)) * 2;
      s16x8 pf = *(const s16x8*)((char*)P + trow * 1024 + (nb ^ ((trow & 7) << 4)));
      o[mf] = mfma16(pf, vf, o[mf]);
    }
  }

#pragma unroll
  for (int mf = 0; mf < 2; mf++) {
#pragma unroll
    for (int q = 0; q < 4; q++) {
      const int t = mf * 16 + ((lane >> 4) << 2) + q;
      const float ov = o[mf][q] * __builtin_amdgcn_rcpf(rst[t]);
      const long long row = (long long)b * 128 + tt * 32 + t;
      headsout[row * 512 + h * 64 + wave * 16 + (lane & 15)] = f2bf(ov);
    }
  }
}

// ---------------------------------------------------------------- launch
extern "C" void kernel_launch(void* const* d_in, const int* in_sizes, int n_in,
                              void* d_out, int out_size, void* d_ws, size_t ws_size,
                              hipStream_t stream) {
  (void)in_sizes; (void)n_in; (void)out_size; (void)ws_size;
  const float* emb  = (const float*)d_in[0];
  const int*   cur  = (const int*)d_in[1];
  const float* ucap = (const float*)d_in[2];
  const float* ubat = (const float*)d_in[3];
  const float* ctim = (const float*)d_in[4];
  const void*  mask = d_in[5];
  const float* Wc   = (const float*)d_in[6];
  const float* Wkvl = (const float*)d_in[7];
  const float* Wstep= (const float*)d_in[8];
  const float* Wout = (const float*)d_in[9];

  char* w = (char*)d_ws;
  size_t off = 0;
  auto take = [&](size_t nbytes) -> char* {
    char* p = w + off;
    off += (nbytes + 255) & ~(size_t)255;
    return p;
  };
  u32* flag            = (u32*)take(4);
  unsigned char* maskb = (unsigned char*)take((size_t)256 * 128 * 64);   // 2 MB
  u16* ebf             = (u16*)take((size_t)256 * 512 * 512 * 2);        // 134 MB
  u16* WkT             = (u16*)take((size_t)1024 * 512 * 2);
  u16* WstepT          = (u16*)take((size_t)512 * 576 * 2);
  u16* W2bf            = (u16*)take((size_t)512 * 512 * 2);
  u16* Woutbf          = (u16*)take((size_t)512 * 512 * 2);
  u16* WfT             = (u16*)take((size_t)512 * 512 * 2);
  float* pmean         = (float*)take((size_t)1024 * 512 * 4);
  float* fixedc        = (float*)take((size_t)256 * 512 * 4);
  u16* Kbuf            = (u16*)take((size_t)256 * 8 * 512 * 64 * 2);     // 134 MB
  u16* Vtbuf           = (u16*)take((size_t)256 * 8 * 64 * 512 * 2);     // 134 MB
  u16* slotA           = (u16*)take((size_t)32768 * 576 * 2);            // 37.7 MB
  u16* slotB           = (u16*)take((size_t)32768 * 512 * 2);            // 33.6 MB
  u16* nextn = slotA;      // alias chain: nextn -> headsout
  u16* query = slotB;      // alias chain: query -> tmp
  u16* headsout = slotA;
  u16* tmpb = slotB;

  detect_mask_kernel<<<1, 256, 0, stream>>>((const u32*)mask, flag);
  maskprep_kernel<<<8192, 256, 0, stream>>>(mask, flag, maskb);
  transpose_cvt_kernel<<<1024, 256, 0, stream>>>(Wkvl, 1536, 0, 512, 512, WkT);
  transpose_cvt_kernel<<<512, 256, 0, stream>>>(Wstep, 512, 0, 515, 576, WstepT);
  slice_cvt_kernel<<<1024, 256, 0, stream>>>(Wkvl, W2bf);
  cvt_bf_kernel<<<1024, 256, 0, stream>>>(Wout, Woutbf);
  gemm128_plain_kernel<<<16, 256, 0, stream>>>(W2bf, Woutbf, WfT);
  cvt_pmean_kernel<<<1024, 256, 0, stream>>>(emb, ebf, pmean);
  fixedctx_kernel<<<256, 256, 0, stream>>>(pmean, Wc, fixedc);
  build_nextn_kernel<<<8192, 256, 0, stream>>>(ebf, cur, ucap, ubat, ctim, nextn);

  // KV projection (persistent): ebf [131072 x 512] x WkT [1024 x 512]
  gemm256_kv_kernel<<<256, 512, 0, stream>>>(ebf, WkT, Kbuf, Vtbuf);
  // query = fixed_context + nextn @ WstepT (K=576, NT=9)
  gemmW_kernel<0><<<512, 512, 0, stream>>>(nextn, WstepT, 576, 576, 9, query, fixedc);
  // attention
  attn_kernel<<<8192, 256, 0, stream>>>(query, Kbuf, Vtbuf, (const u64*)maskb, headsout);
  // tmp = headsout @ WfT (fused Wout*W2), K=512, NT=8
  gemmW_kernel<1><<<512, 512, 0, stream>>>(headsout, WfT, 512, 512, 8, tmpb, nullptr);
  // logits + tanh/mask + log-softmax fused -> f32 d_out
  gemm_lsm_kernel<<<512, 512, 0, stream>>>(ebf, tmpb, (const u64*)maskb, (float*)d_out);
}